// Round 6
// baseline (640.968 us; speedup 1.0000x reference)
//
#include <hip/hip_runtime.h>

typedef _Float16 f16x8 __attribute__((ext_vector_type(8)));
typedef _Float16 f16x4 __attribute__((ext_vector_type(4)));
typedef float f32x4 __attribute__((ext_vector_type(4)));

#define N_PIX 4096
#define C_IN  512
#define BN_INV 0.99999500003749969f  // 1/sqrt(1+1e-5)
#define CCH 64  // conv c-chunk (K per LDS stage)

#define GLOAD_LDS16(g, l)                                        \
  __builtin_amdgcn_global_load_lds(                              \
      (const __attribute__((address_space(1))) void*)(g),        \
      (__attribute__((address_space(3))) void*)(l), 16, 0, 0)

__device__ __forceinline__ f32x4 mfma16(f16x8 a, f16x8 b, f32x4 c) {
  return __builtin_amdgcn_mfma_f32_16x16x32_f16(a, b, c, 0, 0, 0);
}
// NT fragment load: row = base_row + (lane&15), 8 contiguous k at k0 + (lane>>4)*8
__device__ __forceinline__ f16x8 ldnt(const _Float16* base, int row, int ld, int k0, int lane) {
  return *(const f16x8*)(base + (size_t)(row + (lane & 15)) * ld + k0 + ((lane >> 4) << 3));
}

// ---------- x NCHW fp32 -> xT [b][pix][c] fp16 (LDS tile transpose) ----------
__global__ __launch_bounds__(256) void k_xT(const float* __restrict__ x, _Float16* __restrict__ xT) {
  __shared__ float t[32][33];
  int b = blockIdx.z, p0 = blockIdx.x * 32, c0 = blockIdx.y * 32;
  int tx = threadIdx.x & 31, ty = threadIdx.x >> 5;  // 32 x 8
  const float* xb = x + ((size_t)b * C_IN + c0) * N_PIX + p0;
  for (int i = 0; i < 32; i += 8) t[ty + i][tx] = xb[(size_t)(ty + i) * N_PIX + tx];
  __syncthreads();
  _Float16* o = xT + ((size_t)b * N_PIX + p0) * C_IN + c0;
  for (int i = 0; i < 32; i += 8) o[(size_t)(ty + i) * C_IN + tx] = (_Float16)t[tx][ty + i];
}

// ---------- fused fp32 -> fp16 for 4 weight tensors ----------
__global__ __launch_bounds__(256) void k_f2h4(const float* __restrict__ a, _Float16* __restrict__ oa, int na,
                                              const float* __restrict__ b_, _Float16* __restrict__ ob, int nb,
                                              const float* __restrict__ c, _Float16* __restrict__ oc, int nc,
                                              const float* __restrict__ d, _Float16* __restrict__ od, int nd) {
  int i = blockIdx.x * 256 + threadIdx.x;
  if (i < na) { oa[i] = (_Float16)a[i]; return; }
  i -= na;
  if (i < nb) { ob[i] = (_Float16)b_[i]; return; }
  i -= nb;
  if (i < nc) { oc[i] = (_Float16)c[i]; return; }
  i -= nc;
  if (i < nd) od[i] = (_Float16)d[i];
}

// ---------- pack 3x3 dilated conv weights: [conv][tap][oc][c] fp16 ----------
__global__ __launch_bounds__(256) void k_packw(const float* __restrict__ w2, const float* __restrict__ w3,
                                               const float* __restrict__ w4, _Float16* __restrict__ wp) {
  int idx = blockIdx.x * 256 + threadIdx.x;  // 3*9*128*512 = 1769472
  int conv = idx / 589824;
  int t1 = idx % 589824;
  int tap = t1 / 65536;
  int t2 = t1 % 65536;
  int oc = t2 / 512, c = t2 % 512;
  const float* w = (conv == 0) ? w2 : (conv == 1) ? w3 : w4;
  wp[idx] = (_Float16)w[(size_t)(oc * 512 + c) * 9 + tap];
}

// ---------- per (b,c) mean over pixels ----------
__global__ __launch_bounds__(256) void k_mean(const float* __restrict__ x, float* __restrict__ meanv) {
  int c = blockIdx.x, b = blockIdx.y;
  const float* p = x + ((size_t)b * C_IN + c) * N_PIX;
  float s = 0.f;
  for (int i = threadIdx.x; i < N_PIX; i += 256) s += p[i];
  for (int off = 32; off; off >>= 1) s += __shfl_down(s, off);
  __shared__ float ls[4];
  if ((threadIdx.x & 63) == 0) ls[threadIdx.x >> 6] = s;
  __syncthreads();
  if (threadIdx.x == 0) meanv[(size_t)b * C_IN + c] = (ls[0] + ls[1] + ls[2] + ls[3]) * (1.f / N_PIX);
}

// ---------- branch 5: 1x1 conv on pooled vector + BN + ReLU ----------
__global__ void k_p5(const float* __restrict__ w5, const float* __restrict__ meanv,
                     const float* __restrict__ bnS, const float* __restrict__ bnB, _Float16* __restrict__ p5h) {
  int b = blockIdx.x, oc = threadIdx.x;  // 128 threads
  const float* m = meanv + (size_t)b * C_IN;
  const float* w = w5 + (size_t)oc * C_IN;
  float s = 0.f;
  for (int c = 0; c < C_IN; ++c) s += w[c] * m[c];
  float v = fmaxf(s * bnS[oc] * BN_INV + bnB[oc], 0.f);
  p5h[b * 128 + oc] = (_Float16)v;
}

// ---------- broadcast b5 into featT channels [512,640) ----------
__global__ __launch_bounds__(256) void k_b5(const _Float16* __restrict__ p5h, _Float16* __restrict__ featT) {
  int i = blockIdx.x * 256 + threadIdx.x;  // 4*4096*128
  int oc = i & 127, p = (i >> 7) & 4095, b = i >> 19;
  featT[((size_t)b * N_PIX + p) * 640 + 512 + oc] = p5h[b * 128 + oc];
}

// ---------- unified ASPP conv: LDS-staged implicit GEMM ----------
__global__ __launch_bounds__(256, 4) void k_conv(const _Float16* __restrict__ xT, const _Float16* __restrict__ w1h,
                                                 const _Float16* __restrict__ wph, const float* __restrict__ bnS,
                                                 const float* __restrict__ bnB, _Float16* __restrict__ featT) {
  __shared__ _Float16 Ap[3 * 76 * CCH];  // 29184 B
  int y = blockIdx.x;
  int tb = blockIdx.y;
  int task = tb >> 2, b = tb & 3;
  int tid = threadIdx.x, wid = tid >> 6, lane = tid & 63;
  int dil = (task == 0) ? 0 : (task == 1) ? 2 : (task == 2) ? 3 : 6;
  int ntap = task ? 9 : 1;
  int nrow = task ? 3 : 1;
  const _Float16* wt0 = task ? wph + (size_t)(task - 1) * 9 * 128 * C_IN : w1h;
  f32x4 acc[4][2] = {};

  for (int cc = 0; cc < C_IN / CCH; ++cc) {
    int c0 = cc * CCH;
    __syncthreads();  // previous chunk's compute done reading LDS
    if (dil) {
      int nz = nrow * 2 * dil * (CCH / 8);
      for (int i = tid; i < nz; i += 256) {
        int cv = (i & (CCH / 8 - 1)) * 8;
        int t2 = i / (CCH / 8);
        int colh = t2 % (2 * dil);
        int r = t2 / (2 * dil);
        int col = (colh < dil) ? colh : 64 + colh;
        int ba = (((r * 76 + col) * CCH + cv) * 2) ^ ((col & 7) << 4);
        *(f16x8*)((char*)Ap + ba) = (f16x8){};
      }
    }
    int nf = nrow * 64 * (CCH / 8);
    for (int i = tid; i < nf; i += 256) {
      int cv = (i & (CCH / 8 - 1)) * 8;
      int t2 = i / (CCH / 8);
      int px = t2 & 63;
      int r = t2 >> 6;
      int ry = y + (r - 1) * dil;
      f16x8 v = {};
      if ((unsigned)ry < 64u)
        v = *(const f16x8*)(xT + ((size_t)b * N_PIX + ry * 64 + px) * C_IN + c0 + cv);
      int col = dil + px;
      int ba = (((r * 76 + col) * CCH + cv) * 2) ^ ((col & 7) << 4);
      *(f16x8*)((char*)Ap + ba) = v;
    }
    __syncthreads();
    for (int tap = 0; tap < ntap; ++tap) {
      int rsel = tap / 3;
      int dx = (tap % 3 - 1) * dil;
      const _Float16* wt = wt0 + (size_t)tap * 128 * C_IN;
#pragma unroll
      for (int k = 0; k < CCH / 32; ++k) {
        f16x8 wf0 = ldnt(wt, wid * 32, C_IN, c0 + k * 32, lane);
        f16x8 wf1 = ldnt(wt, wid * 32 + 16, C_IN, c0 + k * 32, lane);
        f16x8 af[4];
#pragma unroll
        for (int m = 0; m < 4; ++m) {
          int col = dil + dx + m * 16 + (lane & 15);
          int ch = k * 32 + ((lane >> 4) << 3);
          int ba = (((rsel * 76 + col) * CCH + ch) * 2) ^ ((col & 7) << 4);
          af[m] = *(const f16x8*)((char*)Ap + ba);
        }
#pragma unroll
        for (int m = 0; m < 4; ++m) {
          acc[m][0] = mfma16(af[m], wf0, acc[m][0]);
          acc[m][1] = mfma16(af[m], wf1, acc[m][1]);
        }
      }
    }
  }
  int brOff = task * 128;
  _Float16* F = featT + (size_t)b * N_PIX * 640;
#pragma unroll
  for (int n = 0; n < 2; ++n) {
    int oc = wid * 32 + n * 16 + (lane & 15);
    float inv = bnS[brOff + oc] * BN_INV, bs = bnB[brOff + oc];
#pragma unroll
    for (int m = 0; m < 4; ++m) {
#pragma unroll
      for (int r = 0; r < 4; ++r) {
        int pix = y * 64 + m * 16 + ((lane >> 4) << 2) + r;
        F[(size_t)pix * 640 + brOff + oc] = (_Float16)fmaxf(acc[m][n][r] * inv + bs, 0.f);
      }
    }
  }
}

// ---------- q & k in one dispatch: 1x1 conv 640->128 + bias -> [b][pix][128] fp16 ----------
// p-tile 32: waves split (pw x oc-half); grid (128, 2, 4) = 1024 blocks = 4/CU.
__global__ __launch_bounds__(256) void k_qk(const _Float16* __restrict__ featT, const _Float16* __restrict__ wqh,
                                            const _Float16* __restrict__ wkh, const float* __restrict__ bq,
                                            const float* __restrict__ bk, _Float16* __restrict__ qT,
                                            _Float16* __restrict__ kT) {
  int b = blockIdx.z, which = blockIdx.y, p0 = blockIdx.x * 32;
  const _Float16* wh = which ? wkh : wqh;
  const float* bias = which ? bk : bq;
  _Float16* oT = which ? kT : qT;
  int tid = threadIdx.x, wid = tid >> 6, lane = tid & 63;
  int pw = wid & 1, ocq = wid >> 1;
  const _Float16* A = featT + (size_t)b * N_PIX * 640;
  int pr = p0 + pw * 16;
  f32x4 acc[4] = {};
  for (int kk = 0; kk < 20; ++kk) {
    f16x8 af = ldnt(A, pr, 640, kk * 32, lane);
#pragma unroll
    for (int nn = 0; nn < 4; ++nn) {
      f16x8 bf = ldnt(wh, ocq * 64 + nn * 16, 640, kk * 32, lane);
      acc[nn] = mfma16(af, bf, acc[nn]);
    }
  }
  _Float16* O = oT + (size_t)b * N_PIX * 128;
#pragma unroll
  for (int nn = 0; nn < 4; ++nn) {
    int oc = ocq * 64 + nn * 16 + (lane & 15);
    float bb = bias[oc];
#pragma unroll
    for (int r = 0; r < 4; ++r) {
      int pix = pr + ((lane >> 4) << 2) + r;
      O[(size_t)pix * 128 + oc] = (_Float16)(acc[nn][r] + bb);
    }
  }
}

// ---------- v: 1x1 conv 512->512 + bias -> [b][c][pix] fp16 (channel-major) ----------
__global__ __launch_bounds__(256) void k_v(const _Float16* __restrict__ xT, const _Float16* __restrict__ wvh,
                                           const float* __restrict__ bv, _Float16* __restrict__ vv) {
  int b = blockIdx.z, oc0 = blockIdx.x * 64, p0 = blockIdx.y * 128;
  int tid = threadIdx.x, wid = tid >> 6, lane = tid & 63;
  const _Float16* Bm = xT + (size_t)b * N_PIX * C_IN;
  int or0 = oc0 + wid * 16;
  f32x4 acc[8] = {};
  for (int kk = 0; kk < 16; ++kk) {
    f16x8 af = ldnt(wvh, or0, C_IN, kk * 32, lane);
#pragma unroll
    for (int nn = 0; nn < 8; ++nn) {
      f16x8 bf = ldnt(Bm, p0 + nn * 16, C_IN, kk * 32, lane);
      acc[nn] = mfma16(af, bf, acc[nn]);
    }
  }
  _Float16* V = vv + (size_t)b * C_IN * N_PIX;
#pragma unroll
  for (int r = 0; r < 4; ++r) {
    int oc = or0 + ((lane >> 4) << 2) + r;
    float bb = bv[oc];
#pragma unroll
    for (int nn = 0; nn < 8; ++nn) {
      int pix = p0 + nn * 16 + (lane & 15);
      V[(size_t)oc * N_PIX + pix] = (_Float16)(acc[nn][r] + bb);
    }
  }
}

// ---------- pass 1: partial row max + sumexp over an m-eighth (S^T orientation) ----------
__global__ __launch_bounds__(256) void k_pass1(const _Float16* __restrict__ qT, const _Float16* __restrict__ kT,
                                               float* __restrict__ pmaxP, float* __restrict__ psumP) {
  int b = blockIdx.z, n0 = blockIdx.x * 64, mq = blockIdx.y;
  int tid = threadIdx.x, wid = tid >> 6, lane = tid & 63;
  const _Float16* Q = qT + (size_t)b * N_PIX * 128;
  const _Float16* K = kT + (size_t)b * N_PIX * 128;
  f16x8 qf[4];
#pragma unroll
  for (int kk = 0; kk < 4; ++kk) qf[kk] = ldnt(Q, n0 + wid * 16, 128, kk * 32, lane);
  float mx = -3.4e38f, sm = 0.f;
  for (int it = 0; it < 8; ++it) {
    int m0 = mq * 512 + it * 64;
#pragma unroll
    for (int mm = 0; mm < 4; ++mm) {
      f32x4 s = {};
#pragma unroll
      for (int kk = 0; kk < 4; ++kk) {
        f16x8 kf = ldnt(K, m0 + mm * 16, 128, kk * 32, lane);
        s = mfma16(kf, qf[kk], s);  // S^T: col = n (lane&15), rows = m
      }
      float vmax = fmaxf(fmaxf(s[0], s[1]), fmaxf(s[2], s[3]));
      float newm = fmaxf(mx, vmax);
      sm = sm * __expf(mx - newm) + __expf(s[0] - newm) + __expf(s[1] - newm) +
           __expf(s[2] - newm) + __expf(s[3] - newm);
      mx = newm;
    }
  }
#pragma unroll
  for (int off = 16; off < 64; off <<= 1) {
    float mo = __shfl_xor(mx, off);
    float lo = __shfl_xor(sm, off);
    float mn = fmaxf(mx, mo);
    sm = sm * __expf(mx - mn) + lo * __expf(mo - mn);
    mx = mn;
  }
  if (lane < 16) {
    size_t idx = ((size_t)(b * 8 + mq)) * N_PIX + n0 + wid * 16 + lane;
    pmaxP[idx] = mx;
    psumP[idx] = sm;
  }
}

// ---------- combine 8 m-eighth partials -> rmax, rsum ----------
__global__ __launch_bounds__(256) void k_comb(const float* __restrict__ pmaxP, const float* __restrict__ psumP,
                                              float* __restrict__ rmax, float* __restrict__ rsum) {
  int i = blockIdx.x * 256 + threadIdx.x;  // 4*4096
  int b = i >> 12, n = i & 4095;
  float m = -3.4e38f, l = 0.f;
#pragma unroll
  for (int q = 0; q < 8; ++q) {
    size_t idx = ((size_t)(b * 8 + q)) * N_PIX + n;
    float mq = pmaxP[idx], lq = psumP[idx];
    float nm = fmaxf(m, mq);
    l = l * __expf(m - nm) + lq * __expf(mq - nm);
    m = nm;
  }
  rmax[(size_t)b * N_PIX + n] = m;
  rsum[(size_t)b * N_PIX + n] = l;
}

// ---------- pass 2: fused S^T recompute -> P -> PV -> y = x + gamma*O/sum ----------
// Block = 32 n x 512 c (8 waves), m-tile 128. Single staged K buffer (32KB) +
// double-buffered P (2x8KB) = 48KB -> 2-3 blocks/CU. grid (128, 4) = 512 blocks.
__global__ __launch_bounds__(512, 4) void k_pass2(const _Float16* __restrict__ qT, const _Float16* __restrict__ kT,
                                                  const _Float16* __restrict__ vv, const float* __restrict__ rmax,
                                                  const float* __restrict__ rsum, const float* __restrict__ x,
                                                  const float* __restrict__ gamma, float* __restrict__ out) {
  __shared__ _Float16 Kb[128 * 128];   // 32KB, row 256B, swizzled by (m&7)<<4
  __shared__ _Float16 P[2][32 * 128];  // 2 x 8KB, row 256B, swizzled by (n&7)<<4
  int b = blockIdx.y, n0 = blockIdx.x * 32;
  int tid = threadIdx.x, wid = tid >> 6, lane = tid & 63;
  int ns = wid & 1;   // phaseA n-sub (16 rows of 32)
  int wm = wid >> 1;  // phaseA m-quarter (32 of 128)
  const _Float16* Q = qT + (size_t)b * N_PIX * 128;
  const _Float16* K = kT + (size_t)b * N_PIX * 128;
  const _Float16* V = vv + (size_t)b * C_IN * N_PIX;
  float g = gamma[0];
  f16x8 qf[4];
#pragma unroll
  for (int kk = 0; kk < 4; ++kk) qf[kk] = ldnt(Q, n0 + ns * 16, 128, kk * 32, lane);
  int n_local = ns * 16 + (lane & 15);
  float pmax = rmax[(size_t)b * N_PIX + n0 + n_local];
  f32x4 acc[4][2] = {};  // [cc][nn]

  // stage K-tile `it` into Kb: linear LDS dest, inverse-swizzled global source
  auto stageK = [&](int it) {
    const _Float16* src = K + (size_t)it * 128 * 128;
    int cs = (lane & 15) << 4;  // byte slot within 256B row
#pragma unroll
    for (int i = 0; i < 4; ++i) {
      int rr = wid * 16 + i * 4 + (lane >> 4);
      const char* gp = (const char*)(src + (size_t)rr * 128) + (cs ^ ((rr & 7) << 4));
      char* lp = (char*)Kb + (size_t)(wid * 16 + i * 4) * 256;
      GLOAD_LDS16(gp, lp);
    }
  };

  auto phaseA = [&](int buf) {
#pragma unroll
    for (int mm = 0; mm < 2; ++mm) {
      int row = wm * 32 + mm * 16 + (lane & 15);
      int kboff = (lane >> 4) << 4;
      f32x4 s = {};
#pragma unroll
      for (int kk = 0; kk < 4; ++kk) {
        f16x8 kf = *(const f16x8*)((const char*)Kb + (size_t)row * 256 + ((kk * 64 + kboff) ^ ((row & 7) << 4)));
        s = mfma16(kf, qf[kk], s);  // S^T: col=n, rows=m
      }
      f16x4 pv;
#pragma unroll
      for (int r = 0; r < 4; ++r) pv[r] = (_Float16)__expf(s[r] - pmax);
      int m_local = wm * 32 + mm * 16 + ((lane >> 4) << 2);
      *(f16x4*)((char*)&P[buf][0] + (size_t)n_local * 256 + ((m_local * 2) ^ ((n_local & 7) << 4))) = pv;
    }
  };

  auto phaseB = [&](int it, int buf) {
#pragma unroll
    for (int k2 = 0; k2 < 4; ++k2) {
      f16x8 pb[2];
#pragma unroll
      for (int nn = 0; nn < 2; ++nn) {
        int n = nn * 16 + (lane & 15);
        int mbyte = k2 * 64 + ((lane >> 4) << 4);
        pb[nn] = *(const f16x8*)((char*)&P[buf][0] + (size_t)n * 256 + (mbyte ^ ((n & 7) << 4)));
      }
#pragma unroll
      for (int cc = 0; cc < 4; ++cc) {
        f16x8 af = ldnt(V, wid * 64 + cc * 16, N_PIX, it * 128 + k2 * 32, lane);
        acc[cc][0] = mfma16(af, pb[0], acc[cc][0]);
        acc[cc][1] = mfma16(af, pb[1], acc[cc][1]);
      }
    }
  };

  stageK(0);
  __syncthreads();  // drain stage 0
  phaseA(0);
  __syncthreads();  // P[0] ready; Kb free
  for (int it = 0; it < 32; ++it) {
    if (it < 31) stageK(it + 1);  // overwrite Kb; nobody reads it until next drain
    phaseB(it, it & 1);           // P[it&1] + V
    __syncthreads();              // drains stage(it+1); P[it&1] consumed
    if (it < 31) {
      phaseA((it + 1) & 1);       // reads fresh Kb, writes other P
      __syncthreads();            // P ready; Kb free
    }
  }

  // epilogue: normalize by row sum, y = x + g*O
  float inv_s[2];
#pragma unroll
  for (int nn = 0; nn < 2; ++nn)
    inv_s[nn] = 1.f / rsum[(size_t)b * N_PIX + n0 + nn * 16 + (lane & 15)];
#pragma unroll
  for (int cc = 0; cc < 4; ++cc) {
#pragma unroll
    for (int r = 0; r < 4; ++r) {
      int oc = wid * 64 + cc * 16 + ((lane >> 4) << 2) + r;
#pragma unroll
      for (int nn = 0; nn < 2; ++nn) {
        int pix = n0 + nn * 16 + (lane & 15);
        size_t idx = ((size_t)(b * C_IN + oc)) * N_PIX + pix;
        out[idx] = fmaf(g * inv_s[nn], acc[cc][nn][r], x[idx]);
      }
    }
  }
}

extern "C" void kernel_launch(void* const* d_in, const int* in_sizes, int n_in,
                              void* d_out, int out_size, void* d_ws, size_t ws_size,
                              hipStream_t stream) {
  const float* x = (const float*)d_in[0];
  const float* wa1 = (const float*)d_in[1];
  const float* wa2 = (const float*)d_in[2];
  const float* wa3 = (const float*)d_in[3];
  const float* wa4 = (const float*)d_in[4];
  const float* wa5 = (const float*)d_in[5];
  const float* bnS = (const float*)d_in[6];
  const float* bnB = (const float*)d_in[7];
  const float* wq = (const float*)d_in[8];
  const float* bq = (const float*)d_in[9];
  const float* wk = (const float*)d_in[10];
  const float* bk = (const float*)d_in[11];
  const float* wv = (const float*)d_in[12];
  const float* bv = (const float*)d_in[13];
  const float* gamma = (const float*)d_in[14];

  char* ws = (char*)d_ws;
  size_t off = 0;
  auto alloc = [&](size_t bytes) -> char* {
    char* p = ws + off;
    off = (off + bytes + 255) & ~(size_t)255;
    return p;
  };
  _Float16* xT = (_Float16*)alloc((size_t)4 * 4096 * 512 * 2);
  _Float16* featT = (_Float16*)alloc((size_t)4 * 4096 * 640 * 2);
  _Float16* qT = (_Float16*)alloc((size_t)4 * 4096 * 128 * 2);
  _Float16* kT = (_Float16*)alloc((size_t)4 * 4096 * 128 * 2);
  _Float16* vvp = (_Float16*)alloc((size_t)4 * 512 * 4096 * 2);
  _Float16* w1h = (_Float16*)alloc((size_t)128 * 512 * 2);
  _Float16* wph = (_Float16*)alloc((size_t)3 * 9 * 128 * 512 * 2);
  _Float16* wqh = (_Float16*)alloc((size_t)128 * 640 * 2);
  _Float16* wkh = (_Float16*)alloc((size_t)128 * 640 * 2);
  _Float16* wvh = (_Float16*)alloc((size_t)512 * 512 * 2);
  float* meanv = (float*)alloc((size_t)4 * 512 * 4);
  _Float16* p5h = (_Float16*)alloc((size_t)4 * 128 * 2);
  float* rmax = (float*)alloc((size_t)4 * 4096 * 4);
  float* rsum = (float*)alloc((size_t)4 * 4096 * 4);
  float* pmaxP = (float*)alloc((size_t)4 * 8 * 4096 * 4);
  float* psumP = (float*)alloc((size_t)4 * 8 * 4096 * 4);
  if (off > ws_size) return;  // workspace too small -> fail loudly via wrong output

  float* out = (float*)d_out;

  // stage inputs
  hipLaunchKernelGGL(k_xT, dim3(128, 16, 4), dim3(256), 0, stream, x, xT);
  hipLaunchKernelGGL(k_f2h4, dim3(1920), dim3(256), 0, stream, wa1, w1h, 65536, wq, wqh, 81920, wk, wkh, 81920,
                     wv, wvh, 262144);
  hipLaunchKernelGGL(k_packw, dim3(6912), dim3(256), 0, stream, wa2, wa3, wa4, wph);
  // ASPP
  hipLaunchKernelGGL(k_mean, dim3(512, 4), dim3(256), 0, stream, x, meanv);
  hipLaunchKernelGGL(k_p5, dim3(4), dim3(128), 0, stream, wa5, meanv, bnS + 4 * 128, bnB + 4 * 128, p5h);
  hipLaunchKernelGGL(k_b5, dim3(8192), dim3(256), 0, stream, p5h, featT);
  hipLaunchKernelGGL(k_conv, dim3(64, 16), dim3(256), 0, stream, xT, w1h, wph, bnS, bnB, featT);
  // q, k, v
  hipLaunchKernelGGL(k_qk, dim3(128, 2, 4), dim3(256), 0, stream, featT, wqh, wkh, bq, bk, qT, kT);
  hipLaunchKernelGGL(k_v, dim3(8, 32, 4), dim3(256), 0, stream, xT, wvh, bv, vvp);
  // attention
  hipLaunchKernelGGL(k_pass1, dim3(64, 8, 4), dim3(256), 0, stream, qT, kT, pmaxP, psumP);
  hipLaunchKernelGGL(k_comb, dim3(64), dim3(256), 0, stream, pmaxP, psumP, rmax, rsum);
  hipLaunchKernelGGL(k_pass2, dim3(128, 4), dim3(512), 0, stream, qT, kT, vvp, rmax, rsum, x, gamma, out);
}

// Round 7
// 455.895 us; speedup vs baseline: 1.4060x; 1.4060x over previous
//
#include <hip/hip_runtime.h>

typedef _Float16 f16x8 __attribute__((ext_vector_type(8)));
typedef _Float16 f16x4 __attribute__((ext_vector_type(4)));
typedef float f32x4 __attribute__((ext_vector_type(4)));

#define N_PIX 4096
#define C_IN  512
#define BN_INV 0.99999500003749969f  // 1/sqrt(1+1e-5)
#define CCH 64  // conv c-chunk (K per LDS stage)

#define GLOAD_LDS16(g, l)                                        \
  __builtin_amdgcn_global_load_lds(                              \
      (const __attribute__((address_space(1))) void*)(g),        \
      (__attribute__((address_space(3))) void*)(l), 16, 0, 0)

__device__ __forceinline__ f32x4 mfma16(f16x8 a, f16x8 b, f32x4 c) {
  return __builtin_amdgcn_mfma_f32_16x16x32_f16(a, b, c, 0, 0, 0);
}
// NT fragment load: row = base_row + (lane&15), 8 contiguous k at k0 + (lane>>4)*8
__device__ __forceinline__ f16x8 ldnt(const _Float16* base, int row, int ld, int k0, int lane) {
  return *(const f16x8*)(base + (size_t)(row + (lane & 15)) * ld + k0 + ((lane >> 4) << 3));
}

// ---------- x NCHW fp32 -> xT [b][pix][c] fp16 (LDS tile transpose) ----------
__global__ __launch_bounds__(256) void k_xT(const float* __restrict__ x, _Float16* __restrict__ xT) {
  __shared__ float t[32][33];
  int b = blockIdx.z, p0 = blockIdx.x * 32, c0 = blockIdx.y * 32;
  int tx = threadIdx.x & 31, ty = threadIdx.x >> 5;  // 32 x 8
  const float* xb = x + ((size_t)b * C_IN + c0) * N_PIX + p0;
  for (int i = 0; i < 32; i += 8) t[ty + i][tx] = xb[(size_t)(ty + i) * N_PIX + tx];
  __syncthreads();
  _Float16* o = xT + ((size_t)b * N_PIX + p0) * C_IN + c0;
  for (int i = 0; i < 32; i += 8) o[(size_t)(ty + i) * C_IN + tx] = (_Float16)t[tx][ty + i];
}

// ---------- fused fp32 -> fp16 for 4 weight tensors ----------
__global__ __launch_bounds__(256) void k_f2h4(const float* __restrict__ a, _Float16* __restrict__ oa, int na,
                                              const float* __restrict__ b_, _Float16* __restrict__ ob, int nb,
                                              const float* __restrict__ c, _Float16* __restrict__ oc, int nc,
                                              const float* __restrict__ d, _Float16* __restrict__ od, int nd) {
  int i = blockIdx.x * 256 + threadIdx.x;
  if (i < na) { oa[i] = (_Float16)a[i]; return; }
  i -= na;
  if (i < nb) { ob[i] = (_Float16)b_[i]; return; }
  i -= nb;
  if (i < nc) { oc[i] = (_Float16)c[i]; return; }
  i -= nc;
  if (i < nd) od[i] = (_Float16)d[i];
}

// ---------- pack 3x3 dilated conv weights: [conv][tap][oc][c] fp16 ----------
__global__ __launch_bounds__(256) void k_packw(const float* __restrict__ w2, const float* __restrict__ w3,
                                               const float* __restrict__ w4, _Float16* __restrict__ wp) {
  int idx = blockIdx.x * 256 + threadIdx.x;  // 3*9*128*512 = 1769472
  int conv = idx / 589824;
  int t1 = idx % 589824;
  int tap = t1 / 65536;
  int t2 = t1 % 65536;
  int oc = t2 / 512, c = t2 % 512;
  const float* w = (conv == 0) ? w2 : (conv == 1) ? w3 : w4;
  wp[idx] = (_Float16)w[(size_t)(oc * 512 + c) * 9 + tap];
}

// ---------- per (b,c) mean over pixels ----------
__global__ __launch_bounds__(256) void k_mean(const float* __restrict__ x, float* __restrict__ meanv) {
  int c = blockIdx.x, b = blockIdx.y;
  const float* p = x + ((size_t)b * C_IN + c) * N_PIX;
  float s = 0.f;
  for (int i = threadIdx.x; i < N_PIX; i += 256) s += p[i];
  for (int off = 32; off; off >>= 1) s += __shfl_down(s, off);
  __shared__ float ls[4];
  if ((threadIdx.x & 63) == 0) ls[threadIdx.x >> 6] = s;
  __syncthreads();
  if (threadIdx.x == 0) meanv[(size_t)b * C_IN + c] = (ls[0] + ls[1] + ls[2] + ls[3]) * (1.f / N_PIX);
}

// ---------- branch 5: 1x1 conv on pooled vector + BN + ReLU ----------
__global__ void k_p5(const float* __restrict__ w5, const float* __restrict__ meanv,
                     const float* __restrict__ bnS, const float* __restrict__ bnB, _Float16* __restrict__ p5h) {
  int b = blockIdx.x, oc = threadIdx.x;  // 128 threads
  const float* m = meanv + (size_t)b * C_IN;
  const float* w = w5 + (size_t)oc * C_IN;
  float s = 0.f;
  for (int c = 0; c < C_IN; ++c) s += w[c] * m[c];
  float v = fmaxf(s * bnS[oc] * BN_INV + bnB[oc], 0.f);
  p5h[b * 128 + oc] = (_Float16)v;
}

// ---------- broadcast b5 into featT channels [512,640) ----------
__global__ __launch_bounds__(256) void k_b5(const _Float16* __restrict__ p5h, _Float16* __restrict__ featT) {
  int i = blockIdx.x * 256 + threadIdx.x;  // 4*4096*128
  int oc = i & 127, p = (i >> 7) & 4095, b = i >> 19;
  featT[((size_t)b * N_PIX + p) * 640 + 512 + oc] = p5h[b * 128 + oc];
}

// ---------- unified ASPP conv: LDS-staged implicit GEMM ----------
__global__ __launch_bounds__(256, 4) void k_conv(const _Float16* __restrict__ xT, const _Float16* __restrict__ w1h,
                                                 const _Float16* __restrict__ wph, const float* __restrict__ bnS,
                                                 const float* __restrict__ bnB, _Float16* __restrict__ featT) {
  __shared__ _Float16 Ap[3 * 76 * CCH];  // 29184 B
  int y = blockIdx.x;
  int tb = blockIdx.y;
  int task = tb >> 2, b = tb & 3;
  int tid = threadIdx.x, wid = tid >> 6, lane = tid & 63;
  int dil = (task == 0) ? 0 : (task == 1) ? 2 : (task == 2) ? 3 : 6;
  int ntap = task ? 9 : 1;
  int nrow = task ? 3 : 1;
  const _Float16* wt0 = task ? wph + (size_t)(task - 1) * 9 * 128 * C_IN : w1h;
  f32x4 acc[4][2] = {};

  for (int cc = 0; cc < C_IN / CCH; ++cc) {
    int c0 = cc * CCH;
    __syncthreads();  // previous chunk's compute done reading LDS
    if (dil) {
      int nz = nrow * 2 * dil * (CCH / 8);
      for (int i = tid; i < nz; i += 256) {
        int cv = (i & (CCH / 8 - 1)) * 8;
        int t2 = i / (CCH / 8);
        int colh = t2 % (2 * dil);
        int r = t2 / (2 * dil);
        int col = (colh < dil) ? colh : 64 + colh;
        int ba = (((r * 76 + col) * CCH + cv) * 2) ^ ((col & 7) << 4);
        *(f16x8*)((char*)Ap + ba) = (f16x8){};
      }
    }
    int nf = nrow * 64 * (CCH / 8);
    for (int i = tid; i < nf; i += 256) {
      int cv = (i & (CCH / 8 - 1)) * 8;
      int t2 = i / (CCH / 8);
      int px = t2 & 63;
      int r = t2 >> 6;
      int ry = y + (r - 1) * dil;
      f16x8 v = {};
      if ((unsigned)ry < 64u)
        v = *(const f16x8*)(xT + ((size_t)b * N_PIX + ry * 64 + px) * C_IN + c0 + cv);
      int col = dil + px;
      int ba = (((r * 76 + col) * CCH + cv) * 2) ^ ((col & 7) << 4);
      *(f16x8*)((char*)Ap + ba) = v;
    }
    __syncthreads();
    for (int tap = 0; tap < ntap; ++tap) {
      int rsel = tap / 3;
      int dx = (tap % 3 - 1) * dil;
      const _Float16* wt = wt0 + (size_t)tap * 128 * C_IN;
#pragma unroll
      for (int k = 0; k < CCH / 32; ++k) {
        f16x8 wf0 = ldnt(wt, wid * 32, C_IN, c0 + k * 32, lane);
        f16x8 wf1 = ldnt(wt, wid * 32 + 16, C_IN, c0 + k * 32, lane);
        f16x8 af[4];
#pragma unroll
        for (int m = 0; m < 4; ++m) {
          int col = dil + dx + m * 16 + (lane & 15);
          int ch = k * 32 + ((lane >> 4) << 3);
          int ba = (((rsel * 76 + col) * CCH + ch) * 2) ^ ((col & 7) << 4);
          af[m] = *(const f16x8*)((char*)Ap + ba);
        }
#pragma unroll
        for (int m = 0; m < 4; ++m) {
          acc[m][0] = mfma16(af[m], wf0, acc[m][0]);
          acc[m][1] = mfma16(af[m], wf1, acc[m][1]);
        }
      }
    }
  }
  int brOff = task * 128;
  _Float16* F = featT + (size_t)b * N_PIX * 640;
#pragma unroll
  for (int n = 0; n < 2; ++n) {
    int oc = wid * 32 + n * 16 + (lane & 15);
    float inv = bnS[brOff + oc] * BN_INV, bs = bnB[brOff + oc];
#pragma unroll
    for (int m = 0; m < 4; ++m) {
#pragma unroll
      for (int r = 0; r < 4; ++r) {
        int pix = y * 64 + m * 16 + ((lane >> 4) << 2) + r;
        F[(size_t)pix * 640 + brOff + oc] = (_Float16)fmaxf(acc[m][n][r] * inv + bs, 0.f);
      }
    }
  }
}

// ---------- q & k in one dispatch: 1x1 conv 640->128 + bias -> [b][pix][128] fp16 ----------
__global__ __launch_bounds__(256) void k_qk(const _Float16* __restrict__ featT, const _Float16* __restrict__ wqh,
                                            const _Float16* __restrict__ wkh, const float* __restrict__ bq,
                                            const float* __restrict__ bk, _Float16* __restrict__ qT,
                                            _Float16* __restrict__ kT) {
  int b = blockIdx.z, which = blockIdx.y, p0 = blockIdx.x * 32;
  const _Float16* wh = which ? wkh : wqh;
  const float* bias = which ? bk : bq;
  _Float16* oT = which ? kT : qT;
  int tid = threadIdx.x, wid = tid >> 6, lane = tid & 63;
  int pw = wid & 1, ocq = wid >> 1;
  const _Float16* A = featT + (size_t)b * N_PIX * 640;
  int pr = p0 + pw * 16;
  f32x4 acc[4] = {};
  for (int kk = 0; kk < 20; ++kk) {
    f16x8 af = ldnt(A, pr, 640, kk * 32, lane);
#pragma unroll
    for (int nn = 0; nn < 4; ++nn) {
      f16x8 bf = ldnt(wh, ocq * 64 + nn * 16, 640, kk * 32, lane);
      acc[nn] = mfma16(af, bf, acc[nn]);
    }
  }
  _Float16* O = oT + (size_t)b * N_PIX * 128;
#pragma unroll
  for (int nn = 0; nn < 4; ++nn) {
    int oc = ocq * 64 + nn * 16 + (lane & 15);
    float bb = bias[oc];
#pragma unroll
    for (int r = 0; r < 4; ++r) {
      int pix = pr + ((lane >> 4) << 2) + r;
      O[(size_t)pix * 128 + oc] = (_Float16)(acc[nn][r] + bb);
    }
  }
}

// ---------- v: 1x1 conv 512->512 + bias -> [b][c][pix] fp16 (channel-major) ----------
__global__ __launch_bounds__(256) void k_v(const _Float16* __restrict__ xT, const _Float16* __restrict__ wvh,
                                           const float* __restrict__ bv, _Float16* __restrict__ vv) {
  int b = blockIdx.z, oc0 = blockIdx.x * 64, p0 = blockIdx.y * 128;
  int tid = threadIdx.x, wid = tid >> 6, lane = tid & 63;
  const _Float16* Bm = xT + (size_t)b * N_PIX * C_IN;
  int or0 = oc0 + wid * 16;
  f32x4 acc[8] = {};
  for (int kk = 0; kk < 16; ++kk) {
    f16x8 af = ldnt(wvh, or0, C_IN, kk * 32, lane);
#pragma unroll
    for (int nn = 0; nn < 8; ++nn) {
      f16x8 bf = ldnt(Bm, p0 + nn * 16, C_IN, kk * 32, lane);
      acc[nn] = mfma16(af, bf, acc[nn]);
    }
  }
  _Float16* V = vv + (size_t)b * C_IN * N_PIX;
#pragma unroll
  for (int r = 0; r < 4; ++r) {
    int oc = or0 + ((lane >> 4) << 2) + r;
    float bb = bv[oc];
#pragma unroll
    for (int nn = 0; nn < 8; ++nn) {
      int pix = p0 + nn * 16 + (lane & 15);
      V[(size_t)oc * N_PIX + pix] = (_Float16)(acc[nn][r] + bb);
    }
  }
}

// ---------- one-pass fused attention: S^T -> online softmax -> PV -> y = x + g*O/sum ----------
// Block = 64 n x 512 c (8 waves), m-slab 128/iter. K double-buffered in LDS (2x32KB),
// P single (16KB). phaseA: waves 0-3 (16 n x 128 m each, single owner per row -> scalar
// online max/sum). Defer-max THR=8; rescale factors via fbuf. grid (64, 4) = 256 blocks.
__global__ __launch_bounds__(512, 2) void k_attn(const _Float16* __restrict__ qT, const _Float16* __restrict__ kT,
                                                 const _Float16* __restrict__ vv, const float* __restrict__ x,
                                                 const float* __restrict__ gamma, float* __restrict__ out) {
  __shared__ _Float16 Kb[2][128 * 128];  // 2 x 32KB, row 256B, swizzled by (m&7)<<4
  __shared__ _Float16 P[64 * 128];       // 16KB, row 256B, swizzled by (n&7)<<4
  __shared__ float fbuf[64];             // per-n rescale factor (iter) / final sum (epilogue)
  int b = blockIdx.y, n0 = blockIdx.x * 64;
  int tid = threadIdx.x, wid = tid >> 6, lane = tid & 63;
  const _Float16* Q = qT + (size_t)b * N_PIX * 128;
  const _Float16* K = kT + (size_t)b * N_PIX * 128;
  const _Float16* V = vv + (size_t)b * C_IN * N_PIX;
  float g = gamma[0];
  f16x8 qf[4];
  int n_local = (wid & 3) * 16 + (lane & 15);
  if (wid < 4) {
#pragma unroll
    for (int kk = 0; kk < 4; ++kk) qf[kk] = ldnt(Q, n0 + wid * 16, 128, kk * 32, lane);
  }
  float m_run = -3.4e38f, sm = 0.f;
  f32x4 acc[4][4] = {};  // [cc][nn]

  auto stageK = [&](int it, int buf) {
    const _Float16* src = K + (size_t)it * 128 * 128;
    int cs = (lane & 15) << 4;
#pragma unroll
    for (int i = 0; i < 4; ++i) {
      int rr = wid * 16 + i * 4 + (lane >> 4);
      const char* gp = (const char*)(src + (size_t)rr * 128) + (cs ^ ((rr & 7) << 4));
      char* lp = (char*)&Kb[buf][0] + (size_t)(wid * 16 + i * 4) * 256;
      GLOAD_LDS16(gp, lp);
    }
  };

  // waves 0-3: compute S^T for 16 n x 128 m, online max/sum, P -> LDS, factor -> fbuf
  auto phaseA = [&](int kbuf) {
    const char* kb = (const char*)&Kb[kbuf][0];
    f32x4 s8[8];
#pragma unroll
    for (int mm = 0; mm < 8; ++mm) {
      int row = mm * 16 + (lane & 15);
      int kboff = (lane >> 4) << 4;
      f32x4 s = {};
#pragma unroll
      for (int kk = 0; kk < 4; ++kk) {
        f16x8 kf = *(const f16x8*)(kb + (size_t)row * 256 + ((kk * 64 + kboff) ^ ((row & 7) << 4)));
        s = mfma16(kf, qf[kk], s);  // S^T: col=n, rows=m
      }
      s8[mm] = s;
    }
    float tmx = s8[0][0];
#pragma unroll
    for (int mm = 0; mm < 8; ++mm) {
      tmx = fmaxf(tmx, fmaxf(fmaxf(s8[mm][0], s8[mm][1]), fmaxf(s8[mm][2], s8[mm][3])));
    }
    tmx = fmaxf(tmx, __shfl_xor(tmx, 16));
    tmx = fmaxf(tmx, __shfl_xor(tmx, 32));  // per-n slab max
    float f = 1.f;
    if (tmx > m_run + 8.f) {  // defer-max: tolerate P up to e^8
      f = __expf(m_run - tmx);
      m_run = tmx;
    }
    sm *= f;
    if (lane < 16) fbuf[n_local] = f;
#pragma unroll
    for (int mm = 0; mm < 8; ++mm) {
      f16x4 pv;
#pragma unroll
      for (int r = 0; r < 4; ++r) {
        float p = __expf(s8[mm][r] - m_run);
        sm += p;
        pv[r] = (_Float16)p;
      }
      int m_local = mm * 16 + ((lane >> 4) << 2);
      *(f16x4*)((char*)P + (size_t)n_local * 256 + ((m_local * 2) ^ ((n_local & 7) << 4))) = pv;
    }
  };

  auto phaseB = [&](int it) {
    float f[4];
#pragma unroll
    for (int nn = 0; nn < 4; ++nn) f[nn] = fbuf[nn * 16 + (lane & 15)];
    bool need = (f[0] != 1.f) | (f[1] != 1.f) | (f[2] != 1.f) | (f[3] != 1.f);
    if (__any(need)) {
#pragma unroll
      for (int cc = 0; cc < 4; ++cc)
#pragma unroll
        for (int nn = 0; nn < 4; ++nn) acc[cc][nn] = acc[cc][nn] * f[nn];
    }
#pragma unroll
    for (int k2 = 0; k2 < 4; ++k2) {
      f16x8 pb[4];
#pragma unroll
      for (int nn = 0; nn < 4; ++nn) {
        int n = nn * 16 + (lane & 15);
        int mbyte = k2 * 64 + ((lane >> 4) << 4);
        pb[nn] = *(const f16x8*)((char*)P + (size_t)n * 256 + (mbyte ^ ((n & 7) << 4)));
      }
#pragma unroll
      for (int cc = 0; cc < 4; ++cc) {
        f16x8 af = ldnt(V, wid * 64 + cc * 16, N_PIX, it * 128 + k2 * 32, lane);
#pragma unroll
        for (int nn = 0; nn < 4; ++nn) acc[cc][nn] = mfma16(af, pb[nn], acc[cc][nn]);
      }
    }
  };

  stageK(0, 0);
  __syncthreads();
  for (int it = 0; it < 32; ++it) {
    if (it < 31) stageK(it + 1, (it + 1) & 1);
    if (wid < 4) phaseA(it & 1);
    __syncthreads();  // P + fbuf ready (stage it+1 also drained)
    phaseB(it);
    __syncthreads();  // P consumed; Kb[it&1] free for reuse
  }

  // epilogue: per-n total sum, then y = x + g*O/sum
  if (wid < 4) {
    float st = sm;
    st += __shfl_xor(st, 16);
    st += __shfl_xor(st, 32);
    if (lane < 16) fbuf[n_local] = st;
  }
  __syncthreads();
  float inv_s[4];
#pragma unroll
  for (int nn = 0; nn < 4; ++nn)
    inv_s[nn] = 1.f / fbuf[nn * 16 + (lane & 15)];
#pragma unroll
  for (int cc = 0; cc < 4; ++cc) {
#pragma unroll
    for (int r = 0; r < 4; ++r) {
      int oc = wid * 64 + cc * 16 + ((lane >> 4) << 2) + r;
#pragma unroll
      for (int nn = 0; nn < 4; ++nn) {
        int pix = n0 + nn * 16 + (lane & 15);
        size_t idx = ((size_t)(b * C_IN + oc)) * N_PIX + pix;
        out[idx] = fmaf(g * inv_s[nn], acc[cc][nn][r], x[idx]);
      }
    }
  }
}

extern "C" void kernel_launch(void* const* d_in, const int* in_sizes, int n_in,
                              void* d_out, int out_size, void* d_ws, size_t ws_size,
                              hipStream_t stream) {
  const float* x = (const float*)d_in[0];
  const float* wa1 = (const float*)d_in[1];
  const float* wa2 = (const float*)d_in[2];
  const float* wa3 = (const float*)d_in[3];
  const float* wa4 = (const float*)d_in[4];
  const float* wa5 = (const float*)d_in[5];
  const float* bnS = (const float*)d_in[6];
  const float* bnB = (const float*)d_in[7];
  const float* wq = (const float*)d_in[8];
  const float* bq = (const float*)d_in[9];
  const float* wk = (const float*)d_in[10];
  const float* bk = (const float*)d_in[11];
  const float* wv = (const float*)d_in[12];
  const float* bv = (const float*)d_in[13];
  const float* gamma = (const float*)d_in[14];

  char* ws = (char*)d_ws;
  size_t off = 0;
  auto alloc = [&](size_t bytes) -> char* {
    char* p = ws + off;
    off = (off + bytes + 255) & ~(size_t)255;
    return p;
  };
  _Float16* xT = (_Float16*)alloc((size_t)4 * 4096 * 512 * 2);
  _Float16* featT = (_Float16*)alloc((size_t)4 * 4096 * 640 * 2);
  _Float16* qT = (_Float16*)alloc((size_t)4 * 4096 * 128 * 2);
  _Float16* kT = (_Float16*)alloc((size_t)4 * 4096 * 128 * 2);
  _Float16* vvp = (_Float16*)alloc((size_t)4 * 512 * 4096 * 2);
  _Float16* w1h = (_Float16*)alloc((size_t)128 * 512 * 2);
  _Float16* wph = (_Float16*)alloc((size_t)3 * 9 * 128 * 512 * 2);
  _Float16* wqh = (_Float16*)alloc((size_t)128 * 640 * 2);
  _Float16* wkh = (_Float16*)alloc((size_t)128 * 640 * 2);
  _Float16* wvh = (_Float16*)alloc((size_t)512 * 512 * 2);
  float* meanv = (float*)alloc((size_t)4 * 512 * 4);
  _Float16* p5h = (_Float16*)alloc((size_t)4 * 128 * 2);
  if (off > ws_size) return;  // workspace too small -> fail loudly via wrong output

  float* out = (float*)d_out;

  // stage inputs
  hipLaunchKernelGGL(k_xT, dim3(128, 16, 4), dim3(256), 0, stream, x, xT);
  hipLaunchKernelGGL(k_f2h4, dim3(1920), dim3(256), 0, stream, wa1, w1h, 65536, wq, wqh, 81920, wk, wkh, 81920,
                     wv, wvh, 262144);
  hipLaunchKernelGGL(k_packw, dim3(6912), dim3(256), 0, stream, wa2, wa3, wa4, wph);
  // ASPP
  hipLaunchKernelGGL(k_mean, dim3(512, 4), dim3(256), 0, stream, x, meanv);
  hipLaunchKernelGGL(k_p5, dim3(4), dim3(128), 0, stream, wa5, meanv, bnS + 4 * 128, bnB + 4 * 128, p5h);
  hipLaunchKernelGGL(k_b5, dim3(8192), dim3(256), 0, stream, p5h, featT);
  hipLaunchKernelGGL(k_conv, dim3(64, 16), dim3(256), 0, stream, xT, w1h, wph, bnS, bnB, featT);
  // q, k, v
  hipLaunchKernelGGL(k_qk, dim3(128, 2, 4), dim3(256), 0, stream, featT, wqh, wkh, bq, bk, qT, kT);
  hipLaunchKernelGGL(k_v, dim3(8, 32, 4), dim3(256), 0, stream, xT, wvh, bv, vvp);
  // one-pass attention
  hipLaunchKernelGGL(k_attn, dim3(64, 4), dim3(512), 0, stream, qT, kT, vvp, x, gamma, out);
}

// Round 8
// 448.392 us; speedup vs baseline: 1.4295x; 1.0167x over previous
//
#include <hip/hip_runtime.h>

typedef _Float16 f16x8 __attribute__((ext_vector_type(8)));
typedef _Float16 f16x4 __attribute__((ext_vector_type(4)));
typedef float f32x4 __attribute__((ext_vector_type(4)));

#define N_PIX 4096
#define C_IN  512
#define BN_INV 0.99999500003749969f  // 1/sqrt(1+1e-5)
#define CCH 64  // conv c-chunk (K per LDS stage)

#define GLOAD_LDS16(g, l)                                        \
  __builtin_amdgcn_global_load_lds(                              \
      (const __attribute__((address_space(1))) void*)(g),        \
      (__attribute__((address_space(3))) void*)(l), 16, 0, 0)

__device__ __forceinline__ f32x4 mfma16(f16x8 a, f16x8 b, f32x4 c) {
  return __builtin_amdgcn_mfma_f32_16x16x32_f16(a, b, c, 0, 0, 0);
}
// NT fragment load: row = base_row + (lane&15), 8 contiguous k at k0 + (lane>>4)*8
__device__ __forceinline__ f16x8 ldnt(const _Float16* base, int row, int ld, int k0, int lane) {
  return *(const f16x8*)(base + (size_t)(row + (lane & 15)) * ld + k0 + ((lane >> 4) << 3));
}

// ---------- x NCHW fp32 -> xT [b][pix][c] fp16 (LDS tile transpose) ----------
__global__ __launch_bounds__(256) void k_xT(const float* __restrict__ x, _Float16* __restrict__ xT) {
  __shared__ float t[32][33];
  int b = blockIdx.z, p0 = blockIdx.x * 32, c0 = blockIdx.y * 32;
  int tx = threadIdx.x & 31, ty = threadIdx.x >> 5;  // 32 x 8
  const float* xb = x + ((size_t)b * C_IN + c0) * N_PIX + p0;
  for (int i = 0; i < 32; i += 8) t[ty + i][tx] = xb[(size_t)(ty + i) * N_PIX + tx];
  __syncthreads();
  _Float16* o = xT + ((size_t)b * N_PIX + p0) * C_IN + c0;
  for (int i = 0; i < 32; i += 8) o[(size_t)(ty + i) * C_IN + tx] = (_Float16)t[tx][ty + i];
}

// ---------- fused fp32 -> fp16 for 4 weight tensors ----------
__global__ __launch_bounds__(256) void k_f2h4(const float* __restrict__ a, _Float16* __restrict__ oa, int na,
                                              const float* __restrict__ b_, _Float16* __restrict__ ob, int nb,
                                              const float* __restrict__ c, _Float16* __restrict__ oc, int nc,
                                              const float* __restrict__ d, _Float16* __restrict__ od, int nd) {
  int i = blockIdx.x * 256 + threadIdx.x;
  if (i < na) { oa[i] = (_Float16)a[i]; return; }
  i -= na;
  if (i < nb) { ob[i] = (_Float16)b_[i]; return; }
  i -= nb;
  if (i < nc) { oc[i] = (_Float16)c[i]; return; }
  i -= nc;
  if (i < nd) od[i] = (_Float16)d[i];
}

// ---------- pack 3x3 dilated conv weights: [conv][tap][oc][c] fp16 ----------
__global__ __launch_bounds__(256) void k_packw(const float* __restrict__ w2, const float* __restrict__ w3,
                                               const float* __restrict__ w4, _Float16* __restrict__ wp) {
  int idx = blockIdx.x * 256 + threadIdx.x;  // 3*9*128*512 = 1769472
  int conv = idx / 589824;
  int t1 = idx % 589824;
  int tap = t1 / 65536;
  int t2 = t1 % 65536;
  int oc = t2 / 512, c = t2 % 512;
  const float* w = (conv == 0) ? w2 : (conv == 1) ? w3 : w4;
  wp[idx] = (_Float16)w[(size_t)(oc * 512 + c) * 9 + tap];
}

// ---------- per (b,c) mean over pixels ----------
__global__ __launch_bounds__(256) void k_mean(const float* __restrict__ x, float* __restrict__ meanv) {
  int c = blockIdx.x, b = blockIdx.y;
  const float* p = x + ((size_t)b * C_IN + c) * N_PIX;
  float s = 0.f;
  for (int i = threadIdx.x; i < N_PIX; i += 256) s += p[i];
  for (int off = 32; off; off >>= 1) s += __shfl_down(s, off);
  __shared__ float ls[4];
  if ((threadIdx.x & 63) == 0) ls[threadIdx.x >> 6] = s;
  __syncthreads();
  if (threadIdx.x == 0) meanv[(size_t)b * C_IN + c] = (ls[0] + ls[1] + ls[2] + ls[3]) * (1.f / N_PIX);
}

// ---------- branch 5: 1x1 conv on pooled vector + BN + ReLU ----------
__global__ void k_p5(const float* __restrict__ w5, const float* __restrict__ meanv,
                     const float* __restrict__ bnS, const float* __restrict__ bnB, _Float16* __restrict__ p5h) {
  int b = blockIdx.x, oc = threadIdx.x;  // 128 threads
  const float* m = meanv + (size_t)b * C_IN;
  const float* w = w5 + (size_t)oc * C_IN;
  float s = 0.f;
  for (int c = 0; c < C_IN; ++c) s += w[c] * m[c];
  float v = fmaxf(s * bnS[oc] * BN_INV + bnB[oc], 0.f);
  p5h[b * 128 + oc] = (_Float16)v;
}

// ---------- broadcast b5 into featT channels [512,640) ----------
__global__ __launch_bounds__(256) void k_b5(const _Float16* __restrict__ p5h, _Float16* __restrict__ featT) {
  int i = blockIdx.x * 256 + threadIdx.x;  // 4*4096*128
  int oc = i & 127, p = (i >> 7) & 4095, b = i >> 19;
  featT[((size_t)b * N_PIX + p) * 640 + 512 + oc] = p5h[b * 128 + oc];
}

// ---------- unified ASPP conv: LDS-staged implicit GEMM ----------
__global__ __launch_bounds__(256, 4) void k_conv(const _Float16* __restrict__ xT, const _Float16* __restrict__ w1h,
                                                 const _Float16* __restrict__ wph, const float* __restrict__ bnS,
                                                 const float* __restrict__ bnB, _Float16* __restrict__ featT) {
  __shared__ _Float16 Ap[3 * 76 * CCH];  // 29184 B
  int y = blockIdx.x;
  int tb = blockIdx.y;
  int task = tb >> 2, b = tb & 3;
  int tid = threadIdx.x, wid = tid >> 6, lane = tid & 63;
  int dil = (task == 0) ? 0 : (task == 1) ? 2 : (task == 2) ? 3 : 6;
  int ntap = task ? 9 : 1;
  int nrow = task ? 3 : 1;
  const _Float16* wt0 = task ? wph + (size_t)(task - 1) * 9 * 128 * C_IN : w1h;
  f32x4 acc[4][2] = {};

  for (int cc = 0; cc < C_IN / CCH; ++cc) {
    int c0 = cc * CCH;
    __syncthreads();  // previous chunk's compute done reading LDS
    if (dil) {
      int nz = nrow * 2 * dil * (CCH / 8);
      for (int i = tid; i < nz; i += 256) {
        int cv = (i & (CCH / 8 - 1)) * 8;
        int t2 = i / (CCH / 8);
        int colh = t2 % (2 * dil);
        int r = t2 / (2 * dil);
        int col = (colh < dil) ? colh : 64 + colh;
        int ba = (((r * 76 + col) * CCH + cv) * 2) ^ ((col & 7) << 4);
        *(f16x8*)((char*)Ap + ba) = (f16x8){};
      }
    }
    int nf = nrow * 64 * (CCH / 8);
    for (int i = tid; i < nf; i += 256) {
      int cv = (i & (CCH / 8 - 1)) * 8;
      int t2 = i / (CCH / 8);
      int px = t2 & 63;
      int r = t2 >> 6;
      int ry = y + (r - 1) * dil;
      f16x8 v = {};
      if ((unsigned)ry < 64u)
        v = *(const f16x8*)(xT + ((size_t)b * N_PIX + ry * 64 + px) * C_IN + c0 + cv);
      int col = dil + px;
      int ba = (((r * 76 + col) * CCH + cv) * 2) ^ ((col & 7) << 4);
      *(f16x8*)((char*)Ap + ba) = v;
    }
    __syncthreads();
    for (int tap = 0; tap < ntap; ++tap) {
      int rsel = tap / 3;
      int dx = (tap % 3 - 1) * dil;
      const _Float16* wt = wt0 + (size_t)tap * 128 * C_IN;
#pragma unroll
      for (int k = 0; k < CCH / 32; ++k) {
        f16x8 wf0 = ldnt(wt, wid * 32, C_IN, c0 + k * 32, lane);
        f16x8 wf1 = ldnt(wt, wid * 32 + 16, C_IN, c0 + k * 32, lane);
        f16x8 af[4];
#pragma unroll
        for (int m = 0; m < 4; ++m) {
          int col = dil + dx + m * 16 + (lane & 15);
          int ch = k * 32 + ((lane >> 4) << 3);
          int ba = (((rsel * 76 + col) * CCH + ch) * 2) ^ ((col & 7) << 4);
          af[m] = *(const f16x8*)((char*)Ap + ba);
        }
#pragma unroll
        for (int m = 0; m < 4; ++m) {
          acc[m][0] = mfma16(af[m], wf0, acc[m][0]);
          acc[m][1] = mfma16(af[m], wf1, acc[m][1]);
        }
      }
    }
  }
  int brOff = task * 128;
  _Float16* F = featT + (size_t)b * N_PIX * 640;
#pragma unroll
  for (int n = 0; n < 2; ++n) {
    int oc = wid * 32 + n * 16 + (lane & 15);
    float inv = bnS[brOff + oc] * BN_INV, bs = bnB[brOff + oc];
#pragma unroll
    for (int m = 0; m < 4; ++m) {
#pragma unroll
      for (int r = 0; r < 4; ++r) {
        int pix = y * 64 + m * 16 + ((lane >> 4) << 2) + r;
        F[(size_t)pix * 640 + brOff + oc] = (_Float16)fmaxf(acc[m][n][r] * inv + bs, 0.f);
      }
    }
  }
}

// ---------- q & k in one dispatch: 1x1 conv 640->128 + bias -> [b][pix][128] fp16 ----------
__global__ __launch_bounds__(256) void k_qk(const _Float16* __restrict__ featT, const _Float16* __restrict__ wqh,
                                            const _Float16* __restrict__ wkh, const float* __restrict__ bq,
                                            const float* __restrict__ bk, _Float16* __restrict__ qT,
                                            _Float16* __restrict__ kT) {
  int b = blockIdx.z, which = blockIdx.y, p0 = blockIdx.x * 32;
  const _Float16* wh = which ? wkh : wqh;
  const float* bias = which ? bk : bq;
  _Float16* oT = which ? kT : qT;
  int tid = threadIdx.x, wid = tid >> 6, lane = tid & 63;
  int pw = wid & 1, ocq = wid >> 1;
  const _Float16* A = featT + (size_t)b * N_PIX * 640;
  int pr = p0 + pw * 16;
  f32x4 acc[4] = {};
  for (int kk = 0; kk < 20; ++kk) {
    f16x8 af = ldnt(A, pr, 640, kk * 32, lane);
#pragma unroll
    for (int nn = 0; nn < 4; ++nn) {
      f16x8 bf = ldnt(wh, ocq * 64 + nn * 16, 640, kk * 32, lane);
      acc[nn] = mfma16(af, bf, acc[nn]);
    }
  }
  _Float16* O = oT + (size_t)b * N_PIX * 128;
#pragma unroll
  for (int nn = 0; nn < 4; ++nn) {
    int oc = ocq * 64 + nn * 16 + (lane & 15);
    float bb = bias[oc];
#pragma unroll
    for (int r = 0; r < 4; ++r) {
      int pix = pr + ((lane >> 4) << 2) + r;
      O[(size_t)pix * 128 + oc] = (_Float16)(acc[nn][r] + bb);
    }
  }
}

// ---------- v: 1x1 conv 512->512 + bias -> [b][c][pix] fp16 (channel-major) ----------
__global__ __launch_bounds__(256) void k_v(const _Float16* __restrict__ xT, const _Float16* __restrict__ wvh,
                                           const float* __restrict__ bv, _Float16* __restrict__ vv) {
  int b = blockIdx.z, oc0 = blockIdx.x * 64, p0 = blockIdx.y * 128;
  int tid = threadIdx.x, wid = tid >> 6, lane = tid & 63;
  const _Float16* Bm = xT + (size_t)b * N_PIX * C_IN;
  int or0 = oc0 + wid * 16;
  f32x4 acc[8] = {};
  for (int kk = 0; kk < 16; ++kk) {
    f16x8 af = ldnt(wvh, or0, C_IN, kk * 32, lane);
#pragma unroll
    for (int nn = 0; nn < 8; ++nn) {
      f16x8 bf = ldnt(Bm, p0 + nn * 16, C_IN, kk * 32, lane);
      acc[nn] = mfma16(af, bf, acc[nn]);
    }
  }
  _Float16* V = vv + (size_t)b * C_IN * N_PIX;
#pragma unroll
  for (int r = 0; r < 4; ++r) {
    int oc = or0 + ((lane >> 4) << 2) + r;
    float bb = bv[oc];
#pragma unroll
    for (int nn = 0; nn < 8; ++nn) {
      int pix = p0 + nn * 16 + (lane & 15);
      V[(size_t)oc * N_PIX + pix] = (_Float16)(acc[nn][r] + bb);
    }
  }
}

// ---------- one-pass fused attention, producer/consumer wave specialization ----------
// Block = 64 n x 512 c, 8 waves. Waves 0-3 (producers): QK^T + online softmax for 16 n
// each -> P[(it+1)&1]. Waves 4-7 (consumers): PV over 128 c each from P[it&1].
// K staged 2 tiles ahead (Kb[2]); ONE barrier per iteration. grid (64, 4) = 256 blocks.
__global__ __launch_bounds__(512, 2) void k_attn(const _Float16* __restrict__ qT, const _Float16* __restrict__ kT,
                                                 const _Float16* __restrict__ vv, const float* __restrict__ x,
                                                 const float* __restrict__ gamma, float* __restrict__ out) {
  __shared__ _Float16 Kb[2][128 * 128];  // 2 x 32KB, row 256B, swizzled by (m&7)<<4
  __shared__ _Float16 P[2][64 * 128];    // 2 x 16KB, row 256B, swizzled by (n&7)<<4
  __shared__ float fbuf[2][64];          // per-n rescale factor, per P buffer
  __shared__ float sbuf[64];             // final sums
  int b = blockIdx.y, n0 = blockIdx.x * 64;
  int tid = threadIdx.x, wid = tid >> 6, lane = tid & 63;
  const _Float16* Q = qT + (size_t)b * N_PIX * 128;
  const _Float16* K = kT + (size_t)b * N_PIX * 128;
  const _Float16* V = vv + (size_t)b * C_IN * N_PIX;
  float g = gamma[0];
  f16x8 qf[4];
  int n_local = (wid & 3) * 16 + (lane & 15);
  if (wid < 4) {
#pragma unroll
    for (int kk = 0; kk < 4; ++kk) qf[kk] = ldnt(Q, n0 + wid * 16, 128, kk * 32, lane);
  }
  float m_run = -3.4e38f, sm = 0.f;
  f32x4 acc[8][4];  // consumer: [cc][nn], 128 VGPR
#pragma unroll
  for (int cc = 0; cc < 8; ++cc)
#pragma unroll
    for (int nn = 0; nn < 4; ++nn) acc[cc][nn] = (f32x4){};

  auto stageK = [&](int it, int buf) {  // all 8 waves, 16 rows each
    const _Float16* src = K + (size_t)it * 128 * 128;
    int cs = (lane & 15) << 4;
#pragma unroll
    for (int i = 0; i < 4; ++i) {
      int rr = wid * 16 + i * 4 + (lane >> 4);
      const char* gp = (const char*)(src + (size_t)rr * 128) + (cs ^ ((rr & 7) << 4));
      char* lp = (char*)&Kb[buf][0] + (size_t)(wid * 16 + i * 4) * 256;
      GLOAD_LDS16(gp, lp);
    }
  };

  // producer: S^T for 16 n x 128 m from Kb[it&1], online max/sum, P/fbuf[it&1]
  auto phaseA = [&](int it) {
    int buf = it & 1;
    const char* kb = (const char*)&Kb[buf][0];
    f32x4 s8[8];
#pragma unroll
    for (int mm = 0; mm < 8; ++mm) {
      int row = mm * 16 + (lane & 15);
      int kboff = (lane >> 4) << 4;
      f32x4 s = {};
#pragma unroll
      for (int kk = 0; kk < 4; ++kk) {
        f16x8 kf = *(const f16x8*)(kb + (size_t)row * 256 + ((kk * 64 + kboff) ^ ((row & 7) << 4)));
        s = mfma16(kf, qf[kk], s);  // S^T: col=n, rows=m
      }
      s8[mm] = s;
    }
    float tmx = s8[0][0];
#pragma unroll
    for (int mm = 0; mm < 8; ++mm)
      tmx = fmaxf(tmx, fmaxf(fmaxf(s8[mm][0], s8[mm][1]), fmaxf(s8[mm][2], s8[mm][3])));
    tmx = fmaxf(tmx, __shfl_xor(tmx, 16));
    tmx = fmaxf(tmx, __shfl_xor(tmx, 32));  // per-n slab max
    float f = 1.f;
    if (tmx > m_run + 8.f) {  // defer-max: tolerate P up to e^8
      f = __expf(m_run - tmx);
      m_run = tmx;
    }
    sm *= f;
    if (lane < 16) fbuf[buf][n_local] = f;
#pragma unroll
    for (int mm = 0; mm < 8; ++mm) {
      f16x4 pv;
#pragma unroll
      for (int r = 0; r < 4; ++r) {
        float p = __expf(s8[mm][r] - m_run);
        sm += p;
        pv[r] = (_Float16)p;
      }
      int m_local = mm * 16 + ((lane >> 4) << 2);
      *(f16x4*)((char*)&P[buf][0] + (size_t)n_local * 256 + ((m_local * 2) ^ ((n_local & 7) << 4))) = pv;
    }
  };

  // consumer: PV for 128 c (cw = wid-4) from P[it&1]
  auto phaseB = [&](int it) {
    int buf = it & 1;
    int c0 = (wid - 4) * 128;
    float f[4];
#pragma unroll
    for (int nn = 0; nn < 4; ++nn) f[nn] = fbuf[buf][nn * 16 + (lane & 15)];
    bool need = (f[0] != 1.f) | (f[1] != 1.f) | (f[2] != 1.f) | (f[3] != 1.f);
    if (__any(need)) {
#pragma unroll
      for (int cc = 0; cc < 8; ++cc)
#pragma unroll
        for (int nn = 0; nn < 4; ++nn) acc[cc][nn] = acc[cc][nn] * f[nn];
    }
#pragma unroll
    for (int k2 = 0; k2 < 4; ++k2) {
      f16x8 pb[4];
#pragma unroll
      for (int nn = 0; nn < 4; ++nn) {
        int n = nn * 16 + (lane & 15);
        int mbyte = k2 * 64 + ((lane >> 4) << 4);
        pb[nn] = *(const f16x8*)((char*)&P[buf][0] + (size_t)n * 256 + (mbyte ^ ((n & 7) << 4)));
      }
      __builtin_amdgcn_s_setprio(1);
#pragma unroll
      for (int cc = 0; cc < 8; ++cc) {
        f16x8 af = ldnt(V, c0 + cc * 16, N_PIX, it * 128 + k2 * 32, lane);
#pragma unroll
        for (int nn = 0; nn < 4; ++nn) acc[cc][nn] = mfma16(af, pb[nn], acc[cc][nn]);
      }
      __builtin_amdgcn_s_setprio(0);
    }
  };

  // prologue: stage tiles 0 and 1, compute P for tile 0
  stageK(0, 0);
  stageK(1, 1);
  __syncthreads();
  if (wid < 4) phaseA(0);
  __syncthreads();
  // steady state: ONE barrier per iteration
  for (int it = 0; it < 32; ++it) {
    if (it < 30) stageK(it + 2, it & 1);  // Kb[it&1] was last read in interval it-1
    if (wid < 4) {
      if (it < 31) phaseA(it + 1);
    } else {
      phaseB(it);
    }
    __syncthreads();
  }

  // epilogue: producers publish per-n total sums; consumers write out
  if (wid < 4) {
    float st = sm;
    st += __shfl_xor(st, 16);
    st += __shfl_xor(st, 32);
    if (lane < 16) sbuf[n_local] = st;
  }
  __syncthreads();
  if (wid >= 4) {
    int c0 = (wid - 4) * 128;
    float inv_s[4];
#pragma unroll
    for (int nn = 0; nn < 4; ++nn) inv_s[nn] = 1.f / sbuf[nn * 16 + (lane & 15)];
#pragma unroll
    for (int cc = 0; cc < 8; ++cc) {
#pragma unroll
      for (int r = 0; r < 4; ++r) {
        int oc = c0 + cc * 16 + ((lane >> 4) << 2) + r;
#pragma unroll
        for (int nn = 0; nn < 4; ++nn) {
          int pix = n0 + nn * 16 + (lane & 15);
          size_t idx = ((size_t)(b * C_IN + oc)) * N_PIX + pix;
          out[idx] = fmaf(g * inv_s[nn], acc[cc][nn][r], x[idx]);
        }
      }
    }
  }
}

extern "C" void kernel_launch(void* const* d_in, const int* in_sizes, int n_in,
                              void* d_out, int out_size, void* d_ws, size_t ws_size,
                              hipStream_t stream) {
  const float* x = (const float*)d_in[0];
  const float* wa1 = (const float*)d_in[1];
  const float* wa2 = (const float*)d_in[2];
  const float* wa3 = (const float*)d_in[3];
  const float* wa4 = (const float*)d_in[4];
  const float* wa5 = (const float*)d_in[5];
  const float* bnS = (const float*)d_in[6];
  const float* bnB = (const float*)d_in[7];
  const float* wq = (const float*)d_in[8];
  const float* bq = (const float*)d_in[9];
  const float* wk = (const float*)d_in[10];
  const float* bk = (const float*)d_in[11];
  const float* wv = (const float*)d_in[12];
  const float* bv = (const float*)d_in[13];
  const float* gamma = (const float*)d_in[14];

  char* ws = (char*)d_ws;
  size_t off = 0;
  auto alloc = [&](size_t bytes) -> char* {
    char* p = ws + off;
    off = (off + bytes + 255) & ~(size_t)255;
    return p;
  };
  _Float16* xT = (_Float16*)alloc((size_t)4 * 4096 * 512 * 2);
  _Float16* featT = (_Float16*)alloc((size_t)4 * 4096 * 640 * 2);
  _Float16* qT = (_Float16*)alloc((size_t)4 * 4096 * 128 * 2);
  _Float16* kT = (_Float16*)alloc((size_t)4 * 4096 * 128 * 2);
  _Float16* vvp = (_Float16*)alloc((size_t)4 * 512 * 4096 * 2);
  _Float16* w1h = (_Float16*)alloc((size_t)128 * 512 * 2);
  _Float16* wph = (_Float16*)alloc((size_t)3 * 9 * 128 * 512 * 2);
  _Float16* wqh = (_Float16*)alloc((size_t)128 * 640 * 2);
  _Float16* wkh = (_Float16*)alloc((size_t)128 * 640 * 2);
  _Float16* wvh = (_Float16*)alloc((size_t)512 * 512 * 2);
  float* meanv = (float*)alloc((size_t)4 * 512 * 4);
  _Float16* p5h = (_Float16*)alloc((size_t)4 * 128 * 2);
  if (off > ws_size) return;  // workspace too small -> fail loudly via wrong output

  float* out = (float*)d_out;

  // stage inputs
  hipLaunchKernelGGL(k_xT, dim3(128, 16, 4), dim3(256), 0, stream, x, xT);
  hipLaunchKernelGGL(k_f2h4, dim3(1920), dim3(256), 0, stream, wa1, w1h, 65536, wq, wqh, 81920, wk, wkh, 81920,
                     wv, wvh, 262144);
  hipLaunchKernelGGL(k_packw, dim3(6912), dim3(256), 0, stream, wa2, wa3, wa4, wph);
  // ASPP
  hipLaunchKernelGGL(k_mean, dim3(512, 4), dim3(256), 0, stream, x, meanv);
  hipLaunchKernelGGL(k_p5, dim3(4), dim3(128), 0, stream, wa5, meanv, bnS + 4 * 128, bnB + 4 * 128, p5h);
  hipLaunchKernelGGL(k_b5, dim3(8192), dim3(256), 0, stream, p5h, featT);
  hipLaunchKernelGGL(k_conv, dim3(64, 16), dim3(256), 0, stream, xT, w1h, wph, bnS, bnB, featT);
  // q, k, v
  hipLaunchKernelGGL(k_qk, dim3(128, 2, 4), dim3(256), 0, stream, featT, wqh, wkh, bq, bk, qT, kT);
  hipLaunchKernelGGL(k_v, dim3(8, 32, 4), dim3(256), 0, stream, xT, wvh, bv, vvp);
  // one-pass attention (producer/consumer)
  hipLaunchKernelGGL(k_attn, dim3(64, 4), dim3(512), 0, stream, qT, kT, vvp, x, gamma, out);
}

// Round 9
// 421.222 us; speedup vs baseline: 1.5217x; 1.0645x over previous
//
#include <hip/hip_runtime.h>

typedef _Float16 f16x8 __attribute__((ext_vector_type(8)));
typedef _Float16 f16x4 __attribute__((ext_vector_type(4)));
typedef float f32x4 __attribute__((ext_vector_type(4)));

#define N_PIX 4096
#define C_IN  512
#define BN_INV 0.99999500003749969f  // 1/sqrt(1+1e-5)
#define CCH 64  // conv c-chunk (K per LDS stage)

#define GLOAD_LDS16(g, l)                                        \
  __builtin_amdgcn_global_load_lds(                              \
      (const __attribute__((address_space(1))) void*)(g),        \
      (__attribute__((address_space(3))) void*)(l), 16, 0, 0)

__device__ __forceinline__ f32x4 mfma16(f16x8 a, f16x8 b, f32x4 c) {
  return __builtin_amdgcn_mfma_f32_16x16x32_f16(a, b, c, 0, 0, 0);
}
// NT fragment load: row = base_row + (lane&15), 8 contiguous k at k0 + (lane>>4)*8
__device__ __forceinline__ f16x8 ldnt(const _Float16* base, int row, int ld, int k0, int lane) {
  return *(const f16x8*)(base + (size_t)(row + (lane & 15)) * ld + k0 + ((lane >> 4) << 3));
}

// ---------- x NCHW fp32 -> xT [b][pix][c] fp16 (LDS tile transpose) ----------
__global__ __launch_bounds__(256) void k_xT(const float* __restrict__ x, _Float16* __restrict__ xT) {
  __shared__ float t[32][33];
  int b = blockIdx.z, p0 = blockIdx.x * 32, c0 = blockIdx.y * 32;
  int tx = threadIdx.x & 31, ty = threadIdx.x >> 5;  // 32 x 8
  const float* xb = x + ((size_t)b * C_IN + c0) * N_PIX + p0;
  for (int i = 0; i < 32; i += 8) t[ty + i][tx] = xb[(size_t)(ty + i) * N_PIX + tx];
  __syncthreads();
  _Float16* o = xT + ((size_t)b * N_PIX + p0) * C_IN + c0;
  for (int i = 0; i < 32; i += 8) o[(size_t)(ty + i) * C_IN + tx] = (_Float16)t[tx][ty + i];
}

// ---------- fused fp32 -> fp16 for 4 weight tensors ----------
__global__ __launch_bounds__(256) void k_f2h4(const float* __restrict__ a, _Float16* __restrict__ oa, int na,
                                              const float* __restrict__ b_, _Float16* __restrict__ ob, int nb,
                                              const float* __restrict__ c, _Float16* __restrict__ oc, int nc,
                                              const float* __restrict__ d, _Float16* __restrict__ od, int nd) {
  int i = blockIdx.x * 256 + threadIdx.x;
  if (i < na) { oa[i] = (_Float16)a[i]; return; }
  i -= na;
  if (i < nb) { ob[i] = (_Float16)b_[i]; return; }
  i -= nb;
  if (i < nc) { oc[i] = (_Float16)c[i]; return; }
  i -= nc;
  if (i < nd) od[i] = (_Float16)d[i];
}

// ---------- pack 3x3 dilated conv weights: [conv][tap][oc][c] fp16 ----------
__global__ __launch_bounds__(256) void k_packw(const float* __restrict__ w2, const float* __restrict__ w3,
                                               const float* __restrict__ w4, _Float16* __restrict__ wp) {
  int idx = blockIdx.x * 256 + threadIdx.x;  // 3*9*128*512 = 1769472
  int conv = idx / 589824;
  int t1 = idx % 589824;
  int tap = t1 / 65536;
  int t2 = t1 % 65536;
  int oc = t2 / 512, c = t2 % 512;
  const float* w = (conv == 0) ? w2 : (conv == 1) ? w3 : w4;
  wp[idx] = (_Float16)w[(size_t)(oc * 512 + c) * 9 + tap];
}

// ---------- per (b,c) mean over pixels ----------
__global__ __launch_bounds__(256) void k_mean(const float* __restrict__ x, float* __restrict__ meanv) {
  int c = blockIdx.x, b = blockIdx.y;
  const float* p = x + ((size_t)b * C_IN + c) * N_PIX;
  float s = 0.f;
  for (int i = threadIdx.x; i < N_PIX; i += 256) s += p[i];
  for (int off = 32; off; off >>= 1) s += __shfl_down(s, off);
  __shared__ float ls[4];
  if ((threadIdx.x & 63) == 0) ls[threadIdx.x >> 6] = s;
  __syncthreads();
  if (threadIdx.x == 0) meanv[(size_t)b * C_IN + c] = (ls[0] + ls[1] + ls[2] + ls[3]) * (1.f / N_PIX);
}

// ---------- branch 5: 1x1 conv on pooled vector + BN + ReLU ----------
__global__ void k_p5(const float* __restrict__ w5, const float* __restrict__ meanv,
                     const float* __restrict__ bnS, const float* __restrict__ bnB, _Float16* __restrict__ p5h) {
  int b = blockIdx.x, oc = threadIdx.x;  // 128 threads
  const float* m = meanv + (size_t)b * C_IN;
  const float* w = w5 + (size_t)oc * C_IN;
  float s = 0.f;
  for (int c = 0; c < C_IN; ++c) s += w[c] * m[c];
  float v = fmaxf(s * bnS[oc] * BN_INV + bnB[oc], 0.f);
  p5h[b * 128 + oc] = (_Float16)v;
}

// ---------- broadcast b5 into featT channels [512,640) ----------
__global__ __launch_bounds__(256) void k_b5(const _Float16* __restrict__ p5h, _Float16* __restrict__ featT) {
  int i = blockIdx.x * 256 + threadIdx.x;  // 4*4096*128
  int oc = i & 127, p = (i >> 7) & 4095, b = i >> 19;
  featT[((size_t)b * N_PIX + p) * 640 + 512 + oc] = p5h[b * 128 + oc];
}

// ---------- unified ASPP conv: LDS-staged implicit GEMM ----------
__global__ __launch_bounds__(256, 4) void k_conv(const _Float16* __restrict__ xT, const _Float16* __restrict__ w1h,
                                                 const _Float16* __restrict__ wph, const float* __restrict__ bnS,
                                                 const float* __restrict__ bnB, _Float16* __restrict__ featT) {
  __shared__ _Float16 Ap[3 * 76 * CCH];  // 29184 B
  int y = blockIdx.x;
  int tb = blockIdx.y;
  int task = tb >> 2, b = tb & 3;
  int tid = threadIdx.x, wid = tid >> 6, lane = tid & 63;
  int dil = (task == 0) ? 0 : (task == 1) ? 2 : (task == 2) ? 3 : 6;
  int ntap = task ? 9 : 1;
  int nrow = task ? 3 : 1;
  const _Float16* wt0 = task ? wph + (size_t)(task - 1) * 9 * 128 * C_IN : w1h;
  f32x4 acc[4][2] = {};

  for (int cc = 0; cc < C_IN / CCH; ++cc) {
    int c0 = cc * CCH;
    __syncthreads();  // previous chunk's compute done reading LDS
    if (dil) {
      int nz = nrow * 2 * dil * (CCH / 8);
      for (int i = tid; i < nz; i += 256) {
        int cv = (i & (CCH / 8 - 1)) * 8;
        int t2 = i / (CCH / 8);
        int colh = t2 % (2 * dil);
        int r = t2 / (2 * dil);
        int col = (colh < dil) ? colh : 64 + colh;
        int ba = (((r * 76 + col) * CCH + cv) * 2) ^ ((col & 7) << 4);
        *(f16x8*)((char*)Ap + ba) = (f16x8){};
      }
    }
    int nf = nrow * 64 * (CCH / 8);
    for (int i = tid; i < nf; i += 256) {
      int cv = (i & (CCH / 8 - 1)) * 8;
      int t2 = i / (CCH / 8);
      int px = t2 & 63;
      int r = t2 >> 6;
      int ry = y + (r - 1) * dil;
      f16x8 v = {};
      if ((unsigned)ry < 64u)
        v = *(const f16x8*)(xT + ((size_t)b * N_PIX + ry * 64 + px) * C_IN + c0 + cv);
      int col = dil + px;
      int ba = (((r * 76 + col) * CCH + cv) * 2) ^ ((col & 7) << 4);
      *(f16x8*)((char*)Ap + ba) = v;
    }
    __syncthreads();
    for (int tap = 0; tap < ntap; ++tap) {
      int rsel = tap / 3;
      int dx = (tap % 3 - 1) * dil;
      const _Float16* wt = wt0 + (size_t)tap * 128 * C_IN;
#pragma unroll
      for (int k = 0; k < CCH / 32; ++k) {
        f16x8 wf0 = ldnt(wt, wid * 32, C_IN, c0 + k * 32, lane);
        f16x8 wf1 = ldnt(wt, wid * 32 + 16, C_IN, c0 + k * 32, lane);
        f16x8 af[4];
#pragma unroll
        for (int m = 0; m < 4; ++m) {
          int col = dil + dx + m * 16 + (lane & 15);
          int ch = k * 32 + ((lane >> 4) << 3);
          int ba = (((rsel * 76 + col) * CCH + ch) * 2) ^ ((col & 7) << 4);
          af[m] = *(const f16x8*)((char*)Ap + ba);
        }
#pragma unroll
        for (int m = 0; m < 4; ++m) {
          acc[m][0] = mfma16(af[m], wf0, acc[m][0]);
          acc[m][1] = mfma16(af[m], wf1, acc[m][1]);
        }
      }
    }
  }
  int brOff = task * 128;
  _Float16* F = featT + (size_t)b * N_PIX * 640;
#pragma unroll
  for (int n = 0; n < 2; ++n) {
    int oc = wid * 32 + n * 16 + (lane & 15);
    float inv = bnS[brOff + oc] * BN_INV, bs = bnB[brOff + oc];
#pragma unroll
    for (int m = 0; m < 4; ++m) {
#pragma unroll
      for (int r = 0; r < 4; ++r) {
        int pix = y * 64 + m * 16 + ((lane >> 4) << 2) + r;
        F[(size_t)pix * 640 + brOff + oc] = (_Float16)fmaxf(acc[m][n][r] * inv + bs, 0.f);
      }
    }
  }
}

// ---------- q & k in one dispatch: 1x1 conv 640->128 + bias -> [b][pix][128] fp16 ----------
__global__ __launch_bounds__(256) void k_qk(const _Float16* __restrict__ featT, const _Float16* __restrict__ wqh,
                                            const _Float16* __restrict__ wkh, const float* __restrict__ bq,
                                            const float* __restrict__ bk, _Float16* __restrict__ qT,
                                            _Float16* __restrict__ kT) {
  int b = blockIdx.z, which = blockIdx.y, p0 = blockIdx.x * 32;
  const _Float16* wh = which ? wkh : wqh;
  const float* bias = which ? bk : bq;
  _Float16* oT = which ? kT : qT;
  int tid = threadIdx.x, wid = tid >> 6, lane = tid & 63;
  int pw = wid & 1, ocq = wid >> 1;
  const _Float16* A = featT + (size_t)b * N_PIX * 640;
  int pr = p0 + pw * 16;
  f32x4 acc[4] = {};
  for (int kk = 0; kk < 20; ++kk) {
    f16x8 af = ldnt(A, pr, 640, kk * 32, lane);
#pragma unroll
    for (int nn = 0; nn < 4; ++nn) {
      f16x8 bf = ldnt(wh, ocq * 64 + nn * 16, 640, kk * 32, lane);
      acc[nn] = mfma16(af, bf, acc[nn]);
    }
  }
  _Float16* O = oT + (size_t)b * N_PIX * 128;
#pragma unroll
  for (int nn = 0; nn < 4; ++nn) {
    int oc = ocq * 64 + nn * 16 + (lane & 15);
    float bb = bias[oc];
#pragma unroll
    for (int r = 0; r < 4; ++r) {
      int pix = pr + ((lane >> 4) << 2) + r;
      O[(size_t)pix * 128 + oc] = (_Float16)(acc[nn][r] + bb);
    }
  }
}

// ---------- v: 1x1 conv 512->512 + bias -> [b][c][pix] fp16 (channel-major) ----------
__global__ __launch_bounds__(256) void k_v(const _Float16* __restrict__ xT, const _Float16* __restrict__ wvh,
                                           const float* __restrict__ bv, _Float16* __restrict__ vv) {
  int b = blockIdx.z, oc0 = blockIdx.x * 64, p0 = blockIdx.y * 128;
  int tid = threadIdx.x, wid = tid >> 6, lane = tid & 63;
  const _Float16* Bm = xT + (size_t)b * N_PIX * C_IN;
  int or0 = oc0 + wid * 16;
  f32x4 acc[8] = {};
  for (int kk = 0; kk < 16; ++kk) {
    f16x8 af = ldnt(wvh, or0, C_IN, kk * 32, lane);
#pragma unroll
    for (int nn = 0; nn < 8; ++nn) {
      f16x8 bf = ldnt(Bm, p0 + nn * 16, C_IN, kk * 32, lane);
      acc[nn] = mfma16(af, bf, acc[nn]);
    }
  }
  _Float16* V = vv + (size_t)b * C_IN * N_PIX;
#pragma unroll
  for (int r = 0; r < 4; ++r) {
    int oc = or0 + ((lane >> 4) << 2) + r;
    float bb = bv[oc];
#pragma unroll
    for (int nn = 0; nn < 8; ++nn) {
      int pix = p0 + nn * 16 + (lane & 15);
      V[(size_t)oc * N_PIX + pix] = (_Float16)(acc[nn][r] + bb);
    }
  }
}

// ---------- one-pass fused attention, producer/consumer, 12 waves ----------
// Block = 64 n x 512 c, 768 threads. Waves 0-3 (producers): QK^T + online softmax for
// 16 n each -> P[(it+1)&1]. Waves 4-11 (consumers): PV over 64 c each from P[it&1].
// K staged 2 tiles ahead by waves 0-7; ONE barrier per iteration. grid (64,4) = 256 blocks.
__global__ __launch_bounds__(768, 3) void k_attn(const _Float16* __restrict__ qT, const _Float16* __restrict__ kT,
                                                 const _Float16* __restrict__ vv, const float* __restrict__ x,
                                                 const float* __restrict__ gamma, float* __restrict__ out) {
  __shared__ _Float16 Kb[2][128 * 128];  // 2 x 32KB, row 256B, swizzled by (m&7)<<4
  __shared__ _Float16 P[2][64 * 128];    // 2 x 16KB, row 256B, swizzled by (n&7)<<4
  __shared__ float fbuf[2][64];          // per-n rescale factor, per P buffer
  __shared__ float sbuf[64];             // final sums
  int b = blockIdx.y, n0 = blockIdx.x * 64;
  int tid = threadIdx.x, wid = tid >> 6, lane = tid & 63;
  const _Float16* Q = qT + (size_t)b * N_PIX * 128;
  const _Float16* K = kT + (size_t)b * N_PIX * 128;
  const _Float16* V = vv + (size_t)b * C_IN * N_PIX;
  float g = gamma[0];
  f16x8 qf[4];
  int n_local = (wid & 3) * 16 + (lane & 15);
  if (wid < 4) {
#pragma unroll
    for (int kk = 0; kk < 4; ++kk) qf[kk] = ldnt(Q, n0 + wid * 16, 128, kk * 32, lane);
  }
  float m_run = -3.4e38f, sm = 0.f;
  f32x4 acc[4][4];  // consumer: [cc][nn], 64 VGPR
#pragma unroll
  for (int cc = 0; cc < 4; ++cc)
#pragma unroll
    for (int nn = 0; nn < 4; ++nn) acc[cc][nn] = (f32x4){};

  auto stageK = [&](int it, int buf) {  // waves 0-7, 16 rows each
    const _Float16* src = K + (size_t)it * 128 * 128;
    int cs = (lane & 15) << 4;
#pragma unroll
    for (int i = 0; i < 4; ++i) {
      int rr = wid * 16 + i * 4 + (lane >> 4);
      const char* gp = (const char*)(src + (size_t)rr * 128) + (cs ^ ((rr & 7) << 4));
      char* lp = (char*)&Kb[buf][0] + (size_t)(wid * 16 + i * 4) * 256;
      GLOAD_LDS16(gp, lp);
    }
  };

  // producer: S^T for 16 n x 128 m from Kb[it&1], online max/sum, P/fbuf[it&1]
  auto phaseA = [&](int it) {
    int buf = it & 1;
    const char* kb = (const char*)&Kb[buf][0];
    f32x4 s8[8];
#pragma unroll
    for (int mm = 0; mm < 8; ++mm) {
      int row = mm * 16 + (lane & 15);
      int kboff = (lane >> 4) << 4;
      f32x4 s = {};
#pragma unroll
      for (int kk = 0; kk < 4; ++kk) {
        f16x8 kf = *(const f16x8*)(kb + (size_t)row * 256 + ((kk * 64 + kboff) ^ ((row & 7) << 4)));
        s = mfma16(kf, qf[kk], s);  // S^T: col=n, rows=m
      }
      s8[mm] = s;
    }
    float tmx = s8[0][0];
#pragma unroll
    for (int mm = 0; mm < 8; ++mm)
      tmx = fmaxf(tmx, fmaxf(fmaxf(s8[mm][0], s8[mm][1]), fmaxf(s8[mm][2], s8[mm][3])));
    tmx = fmaxf(tmx, __shfl_xor(tmx, 16));
    tmx = fmaxf(tmx, __shfl_xor(tmx, 32));  // per-n slab max
    float f = 1.f;
    if (tmx > m_run + 8.f) {  // defer-max: tolerate P up to e^8
      f = __expf(m_run - tmx);
      m_run = tmx;
    }
    sm *= f;
    if (lane < 16) fbuf[buf][n_local] = f;
#pragma unroll
    for (int mm = 0; mm < 8; ++mm) {
      f16x4 pv;
#pragma unroll
      for (int r = 0; r < 4; ++r) {
        float p = __expf(s8[mm][r] - m_run);
        sm += p;
        pv[r] = (_Float16)p;
      }
      int m_local = mm * 16 + ((lane >> 4) << 2);
      *(f16x4*)((char*)&P[buf][0] + (size_t)n_local * 256 + ((m_local * 2) ^ ((n_local & 7) << 4))) = pv;
    }
  };

  // consumer: PV for 64 c (wid-4) from P[it&1]
  auto phaseB = [&](int it) {
    int buf = it & 1;
    int c0 = (wid - 4) * 64;
    float f[4];
#pragma unroll
    for (int nn = 0; nn < 4; ++nn) f[nn] = fbuf[buf][nn * 16 + (lane & 15)];
    bool need = (f[0] != 1.f) | (f[1] != 1.f) | (f[2] != 1.f) | (f[3] != 1.f);
    if (__any(need)) {
#pragma unroll
      for (int cc = 0; cc < 4; ++cc)
#pragma unroll
        for (int nn = 0; nn < 4; ++nn) acc[cc][nn] = acc[cc][nn] * f[nn];
    }
#pragma unroll
    for (int k2 = 0; k2 < 4; ++k2) {
      f16x8 pb[4];
#pragma unroll
      for (int nn = 0; nn < 4; ++nn) {
        int n = nn * 16 + (lane & 15);
        int mbyte = k2 * 64 + ((lane >> 4) << 4);
        pb[nn] = *(const f16x8*)((char*)&P[buf][0] + (size_t)n * 256 + (mbyte ^ ((n & 7) << 4)));
      }
      __builtin_amdgcn_s_setprio(1);
#pragma unroll
      for (int cc = 0; cc < 4; ++cc) {
        f16x8 af = ldnt(V, c0 + cc * 16, N_PIX, it * 128 + k2 * 32, lane);
#pragma unroll
        for (int nn = 0; nn < 4; ++nn) acc[cc][nn] = mfma16(af, pb[nn], acc[cc][nn]);
      }
      __builtin_amdgcn_s_setprio(0);
    }
  };

  // prologue: stage tiles 0 and 1, compute P for tile 0
  if (wid < 8) {
    stageK(0, 0);
    stageK(1, 1);
  }
  __syncthreads();
  if (wid < 4) phaseA(0);
  __syncthreads();
  // steady state: ONE barrier per iteration
  for (int it = 0; it < 32; ++it) {
    if (wid < 8 && it < 30) stageK(it + 2, it & 1);  // Kb[it&1] last read in interval it-1
    if (wid < 4) {
      if (it < 31) phaseA(it + 1);
    } else if (wid >= 4) {
      phaseB(it);
    }
    __syncthreads();
  }

  // epilogue: producers publish per-n total sums; consumers write out
  if (wid < 4) {
    float st = sm;
    st += __shfl_xor(st, 16);
    st += __shfl_xor(st, 32);
    if (lane < 16) sbuf[n_local] = st;
  }
  __syncthreads();
  if (wid >= 4) {
    int c0 = (wid - 4) * 64;
    float inv_s[4];
#pragma unroll
    for (int nn = 0; nn < 4; ++nn) inv_s[nn] = 1.f / sbuf[nn * 16 + (lane & 15)];
#pragma unroll
    for (int cc = 0; cc < 4; ++cc) {
#pragma unroll
      for (int r = 0; r < 4; ++r) {
        int oc = c0 + cc * 16 + ((lane >> 4) << 2) + r;
#pragma unroll
        for (int nn = 0; nn < 4; ++nn) {
          int pix = n0 + nn * 16 + (lane & 15);
          size_t idx = ((size_t)(b * C_IN + oc)) * N_PIX + pix;
          out[idx] = fmaf(g * inv_s[nn], acc[cc][nn][r], x[idx]);
        }
      }
    }
  }
}

extern "C" void kernel_launch(void* const* d_in, const int* in_sizes, int n_in,
                              void* d_out, int out_size, void* d_ws, size_t ws_size,
                              hipStream_t stream) {
  const float* x = (const float*)d_in[0];
  const float* wa1 = (const float*)d_in[1];
  const float* wa2 = (const float*)d_in[2];
  const float* wa3 = (const float*)d_in[3];
  const float* wa4 = (const float*)d_in[4];
  const float* wa5 = (const float*)d_in[5];
  const float* bnS = (const float*)d_in[6];
  const float* bnB = (const float*)d_in[7];
  const float* wq = (const float*)d_in[8];
  const float* bq = (const float*)d_in[9];
  const float* wk = (const float*)d_in[10];
  const float* bk = (const float*)d_in[11];
  const float* wv = (const float*)d_in[12];
  const float* bv = (const float*)d_in[13];
  const float* gamma = (const float*)d_in[14];

  char* ws = (char*)d_ws;
  size_t off = 0;
  auto alloc = [&](size_t bytes) -> char* {
    char* p = ws + off;
    off = (off + bytes + 255) & ~(size_t)255;
    return p;
  };
  _Float16* xT = (_Float16*)alloc((size_t)4 * 4096 * 512 * 2);
  _Float16* featT = (_Float16*)alloc((size_t)4 * 4096 * 640 * 2);
  _Float16* qT = (_Float16*)alloc((size_t)4 * 4096 * 128 * 2);
  _Float16* kT = (_Float16*)alloc((size_t)4 * 4096 * 128 * 2);
  _Float16* vvp = (_Float16*)alloc((size_t)4 * 512 * 4096 * 2);
  _Float16* w1h = (_Float16*)alloc((size_t)128 * 512 * 2);
  _Float16* wph = (_Float16*)alloc((size_t)3 * 9 * 128 * 512 * 2);
  _Float16* wqh = (_Float16*)alloc((size_t)128 * 640 * 2);
  _Float16* wkh = (_Float16*)alloc((size_t)128 * 640 * 2);
  _Float16* wvh = (_Float16*)alloc((size_t)512 * 512 * 2);
  float* meanv = (float*)alloc((size_t)4 * 512 * 4);
  _Float16* p5h = (_Float16*)alloc((size_t)4 * 128 * 2);
  if (off > ws_size) return;  // workspace too small -> fail loudly via wrong output

  float* out = (float*)d_out;

  // stage inputs
  hipLaunchKernelGGL(k_xT, dim3(128, 16, 4), dim3(256), 0, stream, x, xT);
  hipLaunchKernelGGL(k_f2h4, dim3(1920), dim3(256), 0, stream, wa1, w1h, 65536, wq, wqh, 81920, wk, wkh, 81920,
                     wv, wvh, 262144);
  hipLaunchKernelGGL(k_packw, dim3(6912), dim3(256), 0, stream, wa2, wa3, wa4, wph);
  // ASPP
  hipLaunchKernelGGL(k_mean, dim3(512, 4), dim3(256), 0, stream, x, meanv);
  hipLaunchKernelGGL(k_p5, dim3(4), dim3(128), 0, stream, wa5, meanv, bnS + 4 * 128, bnB + 4 * 128, p5h);
  hipLaunchKernelGGL(k_b5, dim3(8192), dim3(256), 0, stream, p5h, featT);
  hipLaunchKernelGGL(k_conv, dim3(64, 16), dim3(256), 0, stream, xT, w1h, wph, bnS, bnB, featT);
  // q, k, v
  hipLaunchKernelGGL(k_qk, dim3(128, 2, 4), dim3(256), 0, stream, featT, wqh, wkh, bq, bk, qT, kT);
  hipLaunchKernelGGL(k_v, dim3(8, 32, 4), dim3(256), 0, stream, xT, wvh, bv, vvp);
  // one-pass attention (producer/consumer, 12 waves)
  hipLaunchKernelGGL(k_attn, dim3(64, 4), dim3(768), 0, stream, qT, kT, vvp, x, gamma, out);
}